// Round 13
// baseline (452.395 us; speedup 1.0000x reference)
//
#include <hip/hip_runtime.h>
#include <hip/hip_bf16.h>
#include <math.h>

// Problem constants
#define Fn   128
#define Wn   9
#define Bn   16
#define En   6
#define NHn  3
#define NLn  3
#define FFDn 12
#define HIDn 768       // F*E
#define Sn   1152      // W*F
#define TOPMn 99
#define DHn  2

__device__ __forceinline__ float sigmoidf_(float x) {
    return 1.0f / (1.0f + __expf(-x));
}

// order-preserving float<->uint key mapping (total order)
__device__ __forceinline__ unsigned f2k(float f) {
    unsigned b = __float_as_uint(f);
    return (b & 0x80000000u) ? ~b : (b | 0x80000000u);
}
__device__ __forceinline__ float k2f(unsigned k) {
    return __uint_as_float((k & 0x80000000u) ? (k & 0x7FFFFFFFu) : ~k);
}

// ---------------------------------------------------------------------------
// K1: AutoDis + positional embedding -> x [B,S,E], fused layer-0 QKV
// ---------------------------------------------------------------------------
__global__ __launch_bounds__(256) void k_autodis_qkv(
    const float* __restrict__ src, const float* __restrict__ w1w,
    const float* __restrict__ w1b, const float* __restrict__ w2w,
    const float* __restrict__ w2b, const float* __restrict__ meta,
    const float* __restrict__ pos, const float* __restrict__ Wq,
    const float* __restrict__ Wk, const float* __restrict__ Wv,
    const float* __restrict__ bq, const float* __restrict__ bk,
    const float* __restrict__ bv,
    float* __restrict__ x, float* __restrict__ q,
    float* __restrict__ k, float* __restrict__ v)
{
    int i = blockIdx.x * 256 + threadIdx.x;   // over W*B*F = 18432
    if (i >= Wn * Bn * Fn) return;
    int f = i & 127;
    int b = (i >> 7) & 15;
    int w = i >> 11;

    float s = src[i];
    float h1[6];
#pragma unroll
    for (int j = 0; j < 6; ++j) {
        float t = fmaf(s, w1w[f*6+j], w1b[f*6+j]);
        h1[j] = t >= 0.f ? t : 0.01f * t;          // LeakyReLU 0.01
    }
    float tt[6];
    float mx = -3.0e38f;
#pragma unroll
    for (int j = 0; j < 6; ++j) {
        float a = w2b[f*6+j];
#pragma unroll
        for (int kk = 0; kk < 6; ++kk) a = fmaf(h1[kk], w2w[(f*6+kk)*6+j], a);
        a = fmaf(0.5f, h1[j], a);                  // + CTRL*h1
        tt[j] = a;
        mx = fmaxf(mx, a);
    }
    float e[6], sum = 0.f;
#pragma unroll
    for (int j = 0; j < 6; ++j) { e[j] = __expf((tt[j]-mx) * 1e5f); sum += e[j]; }
    float isum = 1.f / sum;
    int srow = w*Fn + f;
    size_t row = (size_t)(b*Sn + srow);
    float xr[6];
#pragma unroll
    for (int ee = 0; ee < 6; ++ee) {
        float a = 0.f;
#pragma unroll
        for (int kk = 0; kk < 6; ++kk) a = fmaf(e[kk], meta[(f*6+kk)*6+ee], a);
        xr[ee] = fmaf(a * isum, 2.449489742783178f, pos[srow*6+ee]);
        x[row*6 + ee] = xr[ee];
    }
    // layer-0 QKV
#pragma unroll
    for (int j = 0; j < 6; ++j) {
        float aq = bq[j], ak = bk[j], av = bv[j];
#pragma unroll
        for (int ee = 0; ee < 6; ++ee) {
            aq = fmaf(xr[ee], Wq[ee*6+j], aq);
            ak = fmaf(xr[ee], Wk[ee*6+j], ak);
            av = fmaf(xr[ee], Wv[ee*6+j], av);
        }
        q[row*6+j] = aq; k[row*6+j] = ak; v[row*6+j] = av;
    }
}

// Exact top-99 threshold search (verified R10/R12 semantics), as a macro so
// the score array stays in registers (no pointer-to-array scratch hazard).
// Invariant: cl=cnt(>=flo)>=99>ch=cnt(>=fhi), exact ballot counts.
// Exits: empty strict interior -> thr=flo (== s_99 incl. ties);
//        quickselect == branch -> thr == s_99 bit-exact.
#define TOPK_SEARCH(SC, MXv, MUv, SGv, THR_OUT)                               \
  do {                                                                        \
    float flo = -3.0e38f;                                                     \
    float fhi = k2f(f2k(MXv) + 1u);                                           \
    int cl = 1152, ch = 0;                                                    \
    float thr_ = flo;                                                         \
    bool resolved = false;                                                    \
    float lastf = 0.f; int lastc = 0;                                         \
    _Pragma("unroll 1")                                                       \
    for (int s = 0; s < 2; ++s) {                                             \
        unsigned klo = f2k(flo), khi = f2k(fhi);                              \
        if (khi - klo <= 1u) break;                                           \
        float t = (s == 0) ? fmaf(1.366f, SGv, MUv)                           \
                           : fmaf((float)(lastc - 99)*0.005543f, SGv, lastf); \
        unsigned tk = f2k(t);                                                 \
        if (tk <= klo) tk = klo + 1u; else if (tk >= khi) tk = khi - 1u;      \
        t = k2f(tk);                                                          \
        int cnt = 0;                                                          \
        _Pragma("unroll")                                                     \
        for (int j = 0; j < 18; ++j)                                          \
            cnt += (int)__popcll(__ballot(SC[j] >= t));                       \
        if (cnt >= 99) { flo = t; cl = cnt; } else { fhi = t; ch = cnt; }     \
        lastf = t; lastc = cnt;                                               \
    }                                                                         \
    _Pragma("unroll 1")                                                       \
    for (int it = 0; it < 200 && (cl - ch) > 128; ++it) {                     \
        float cval = 0.f; bool have = false;                                  \
        _Pragma("unroll")                                                     \
        for (int j = 0; j < 18; ++j) {                                        \
            bool c = (SC[j] > flo) && (SC[j] < fhi);                          \
            cval = c ? SC[j] : cval;                                          \
            have = have || c;                                                 \
        }                                                                     \
        unsigned long long m = __ballot(have);                                \
        if (m == 0ull) { thr_ = flo; resolved = true; break; }                \
        float t;                                                              \
        if ((it & 3) == 3) {                                                  \
            unsigned klo = f2k(flo), khi = f2k(fhi);                          \
            unsigned tk = klo + ((khi - klo) >> 1);                           \
            if (tk <= klo) tk = klo + 1u;                                     \
            if (tk >= khi) tk = khi - 1u;                                     \
            t = k2f(tk);                                                      \
        } else {                                                              \
            unsigned rr = (unsigned)(it * 23) & 63u;                          \
            unsigned long long rot =                                          \
                rr ? ((m >> rr) | (m << (64u - rr))) : m;                     \
            int lsel = (__builtin_ctzll(rot) + (int)rr) & 63;                 \
            t = __shfl(cval, lsel);                                           \
        }                                                                     \
        int cnt = 0;                                                          \
        _Pragma("unroll")                                                     \
        for (int j = 0; j < 18; ++j)                                          \
            cnt += (int)__popcll(__ballot(SC[j] >= t));                       \
        if (cnt >= 99) { flo = t; cl = cnt; } else { fhi = t; ch = cnt; }     \
    }                                                                         \
    if (!resolved) {                                                          \
        int ncand = cl - ch;                                                  \
        int myn = 0;                                                          \
        _Pragma("unroll")                                                     \
        for (int j = 0; j < 18; ++j)                                          \
            myn += ((SC[j] >= flo) && (SC[j] < fhi)) ? 1 : 0;                 \
        int pre = myn;                                                        \
        _Pragma("unroll")                                                     \
        for (int d = 1; d < 64; d <<= 1) {                                    \
            int t2 = __shfl_up(pre, d);                                       \
            if (lane >= d) pre += t2;                                         \
        }                                                                     \
        pre -= myn;                                                           \
        int idx = pre;                                                        \
        _Pragma("unroll")                                                     \
        for (int j = 0; j < 18; ++j) {                                        \
            if ((SC[j] >= flo) && (SC[j] < fhi)) {                            \
                if (idx < 128) cbuf[wave][idx] = SC[j];                       \
                ++idx;                                                        \
            }                                                                 \
        }                                                                     \
        __builtin_amdgcn_wave_barrier();                                      \
        float v0 = (lane < ncand)      ? cbuf[wave][lane]      : 0.f;         \
        float v1 = (lane + 64 < ncand) ? cbuf[wave][lane + 64] : 0.f;         \
        unsigned long long a0 = __ballot(lane < ncand);                       \
        unsigned long long a1 = __ballot(lane + 64 < ncand);                  \
        int kp = 99 - ch;                                                     \
        _Pragma("unroll 1")                                                   \
        for (int it = 0; it < 200; ++it) {                                    \
            bool useA = (a0 != 0ull);                                         \
            unsigned long long m = useA ? a0 : a1;                            \
            unsigned rr = (unsigned)(it * 23) & 63u;                          \
            unsigned long long rot =                                          \
                rr ? ((m >> rr) | (m << (64u - rr))) : m;                     \
            int lsel = (__builtin_ctzll(rot) + (int)rr) & 63;                 \
            float piv = useA ? __shfl(v0, lsel) : __shfl(v1, lsel);           \
            unsigned long long bgt0 = __ballot(v0 > piv) & a0;                \
            unsigned long long bgt1 = __ballot(v1 > piv) & a1;                \
            unsigned long long beq0 = __ballot(v0 == piv) & a0;               \
            unsigned long long beq1 = __ballot(v1 == piv) & a1;               \
            int cgt = (int)__popcll(bgt0) + (int)__popcll(bgt1);              \
            int ceq = (int)__popcll(beq0) + (int)__popcll(beq1);              \
            if (kp <= cgt) { a0 = bgt0; a1 = bgt1; }                          \
            else if (kp <= cgt + ceq) { thr_ = piv; break; }                  \
            else {                                                            \
                kp -= cgt + ceq;                                              \
                a0 &= __ballot(v0 < piv);                                     \
                a1 &= __ballot(v1 < piv);                                     \
            }                                                                 \
        }                                                                     \
    }                                                                         \
    THR_OUT = thr_;                                                           \
  } while (0)

// ---------------------------------------------------------------------------
// K3: fused attention. R12-verified search; NEW: 2 rows per wave pass
// (2 pairs covering the wave's 4 rows). Shared per pair: every Ks read in
// the score pass, one 6-value shfl reduction chain, every Vs read in PV.
// Searches run sequentially per row (identical verified semantics).
// ---------------------------------------------------------------------------
__global__ __launch_bounds__(256) void k_attn(
    const float* __restrict__ q, const float* __restrict__ kbuf,
    const float* __restrict__ vbuf, float* __restrict__ o)
{
    __shared__ float2 Ks[Sn];
    __shared__ float2 Vs[Sn];
    __shared__ float cbuf[4][128];
    int bx = blockIdx.x;
    int qc = bx % 72;              // 72 q-chunks of 16 rows
    int bh = bx / 72;
    int h = bh % NHn, b = bh / NHn;
    int lane = threadIdx.x & 63, wave = threadIdx.x >> 6;

    for (int idx = threadIdx.x; idx < Sn; idx += 256) {
        Ks[idx] = *(const float2*)(kbuf + ((size_t)(b*Sn + idx))*6 + h*2);
        Vs[idx] = *(const float2*)(vbuf + ((size_t)(b*Sn + idx))*6 + h*2);
    }
    __syncthreads();

    const float scale = 0.70710678118654752f;  // 1/sqrt(DH)
#pragma unroll 1
    for (int pr = 0; pr < 2; ++pr) {
        int qrow = qc*16 + wave*4 + pr*2;      // rows qrow, qrow+1
        const float* qp = q + ((size_t)(b*Sn + qrow))*6 + h*2;
        float q0x = qp[0]*scale, q0y = qp[1]*scale;
        float q1x = qp[6]*scale, q1y = qp[7]*scale;

        float sc0[18], sc1[18];
        float mx0 = -3.0e38f, s1_0 = 0.f, s2_0 = 0.f;
        float mx1 = -3.0e38f, s1_1 = 0.f, s2_1 = 0.f;
#pragma unroll
        for (int j = 0; j < 18; ++j) {
            float2 kk = Ks[lane + 64*j];
            float sA = fmaf(q0x, kk.x, q0y*kk.y);
            float sB = fmaf(q1x, kk.x, q1y*kk.y);
            sc0[j] = sA; sc1[j] = sB;
            mx0 = fmaxf(mx0, sA); s1_0 += sA; s2_0 = fmaf(sA, sA, s2_0);
            mx1 = fmaxf(mx1, sB); s1_1 += sB; s2_1 = fmaf(sB, sB, s2_1);
        }
        for (int off = 32; off; off >>= 1) {
            mx0 = fmaxf(mx0, __shfl_xor(mx0, off));
            s1_0 += __shfl_xor(s1_0, off);
            s2_0 += __shfl_xor(s2_0, off);
            mx1 = fmaxf(mx1, __shfl_xor(mx1, off));
            s1_1 += __shfl_xor(s1_1, off);
            s2_1 += __shfl_xor(s2_1, off);
        }
        mx0 = __uint_as_float(__builtin_amdgcn_readfirstlane(__float_as_uint(mx0)));
        s1_0 = __uint_as_float(__builtin_amdgcn_readfirstlane(__float_as_uint(s1_0)));
        s2_0 = __uint_as_float(__builtin_amdgcn_readfirstlane(__float_as_uint(s2_0)));
        mx1 = __uint_as_float(__builtin_amdgcn_readfirstlane(__float_as_uint(mx1)));
        s1_1 = __uint_as_float(__builtin_amdgcn_readfirstlane(__float_as_uint(s1_1)));
        s2_1 = __uint_as_float(__builtin_amdgcn_readfirstlane(__float_as_uint(s2_1)));

        const float invN = 1.0f/1152.0f;
        float mu0 = s1_0*invN;
        float sg0 = sqrtf(fmaxf(fmaf(-mu0, mu0, s2_0*invN), 0.f) + 1e-20f);
        float mu1 = s1_1*invN;
        float sg1 = sqrtf(fmaxf(fmaf(-mu1, mu1, s2_1*invN), 0.f) + 1e-20f);

        float thr0, thr1;
        TOPK_SEARCH(sc0, mx0, mu0, sg0, thr0);
        TOPK_SEARCH(sc1, mx1, mu1, sg1, thr1);

        float ps0 = 0.f, ox0 = 0.f, oy0 = 0.f;
        float ps1 = 0.f, ox1 = 0.f, oy1 = 0.f;
#pragma unroll
        for (int j = 0; j < 18; ++j) {
            float2 vv = Vs[lane + 64*j];
            float p0 = (sc0[j] >= thr0) ? __expf(sc0[j] - mx0) : 0.f;
            float p1 = (sc1[j] >= thr1) ? __expf(sc1[j] - mx1) : 0.f;
            ps0 += p0; ox0 = fmaf(p0, vv.x, ox0); oy0 = fmaf(p0, vv.y, oy0);
            ps1 += p1; ox1 = fmaf(p1, vv.x, ox1); oy1 = fmaf(p1, vv.y, oy1);
        }
        for (int off = 32; off; off >>= 1) {
            ps0 += __shfl_xor(ps0, off);
            ox0 += __shfl_xor(ox0, off);
            oy0 += __shfl_xor(oy0, off);
            ps1 += __shfl_xor(ps1, off);
            ox1 += __shfl_xor(ox1, off);
            oy1 += __shfl_xor(oy1, off);
        }
        if (lane == 0) {
            float inv0 = 1.f / ps0, inv1 = 1.f / ps1;
            float* op = o + ((size_t)(b*Sn + qrow))*6 + h*2;
            op[0] = ox0*inv0; op[1] = oy0*inv0;
            op[6] = ox1*inv1; op[7] = oy1*inv1;
        }
    }
}

// ---------------------------------------------------------------------------
// K4: o@Wo + residual + LN1 + FFN + residual + LN2 (+ optional next-layer QKV)
// ---------------------------------------------------------------------------
__global__ __launch_bounds__(256) void k_post(
    const float* __restrict__ xin, const float* __restrict__ ob,
    const float* __restrict__ Wo, const float* __restrict__ bo,
    const float* __restrict__ l1s, const float* __restrict__ l1b,
    const float* __restrict__ W1, const float* __restrict__ b1,
    const float* __restrict__ W2, const float* __restrict__ b2,
    const float* __restrict__ l2s, const float* __restrict__ l2b,
    float* __restrict__ xout,
    const float* __restrict__ Wq2, const float* __restrict__ Wk2,
    const float* __restrict__ Wv2, const float* __restrict__ bq2,
    const float* __restrict__ bk2, const float* __restrict__ bv2,
    float* __restrict__ q, float* __restrict__ k, float* __restrict__ v)
{
    int i = blockIdx.x * 256 + threadIdx.x;
    if (i >= Bn * Sn) return;
    float xr[6], orow[6];
#pragma unroll
    for (int e = 0; e < 6; ++e) {
        xr[e]   = xin[(size_t)i*6 + e];
        orow[e] = ob[(size_t)i*6 + e];
    }
    float rbuf[6];
#pragma unroll
    for (int j = 0; j < 6; ++j) {
        float a = bo[j];
#pragma unroll
        for (int e = 0; e < 6; ++e) a = fmaf(orow[e], Wo[e*6+j], a);
        rbuf[j] = xr[j] + a;
    }
    // LN1
    float mean = 0.f;
#pragma unroll
    for (int j = 0; j < 6; ++j) mean += rbuf[j];
    mean *= (1.f/6.f);
    float var = 0.f;
#pragma unroll
    for (int j = 0; j < 6; ++j) { float d = rbuf[j]-mean; var = fmaf(d, d, var); }
    var *= (1.f/6.f);
    float inv = rsqrtf(var + 1e-5f);
    float y1[6];
#pragma unroll
    for (int j = 0; j < 6; ++j) y1[j] = fmaf((rbuf[j]-mean)*inv, l1s[j], l1b[j]);
    // FFN
    float ff[12];
#pragma unroll
    for (int jj = 0; jj < 12; ++jj) {
        float a = b1[jj];
#pragma unroll
        for (int e = 0; e < 6; ++e) a = fmaf(y1[e], W1[e*12+jj], a);
        ff[jj] = fmaxf(a, 0.f);
    }
#pragma unroll
    for (int j = 0; j < 6; ++j) {
        float a = b2[j];
#pragma unroll
        for (int kk = 0; kk < 12; ++kk) a = fmaf(ff[kk], W2[kk*6+j], a);
        rbuf[j] = y1[j] + a;
    }
    // LN2
    mean = 0.f;
#pragma unroll
    for (int j = 0; j < 6; ++j) mean += rbuf[j];
    mean *= (1.f/6.f);
    var = 0.f;
#pragma unroll
    for (int j = 0; j < 6; ++j) { float d = rbuf[j]-mean; var = fmaf(d, d, var); }
    var *= (1.f/6.f);
    inv = rsqrtf(var + 1e-5f);
    float xo[6];
#pragma unroll
    for (int j = 0; j < 6; ++j) {
        xo[j] = fmaf((rbuf[j]-mean)*inv, l2s[j], l2b[j]);
        xout[(size_t)i*6 + j] = xo[j];
    }
    if (Wq2) {  // fused next-layer QKV (wave-uniform branch)
#pragma unroll
        for (int j = 0; j < 6; ++j) {
            float aq = bq2[j], ak = bk2[j], av = bv2[j];
#pragma unroll
            for (int e = 0; e < 6; ++e) {
                aq = fmaf(xo[e], Wq2[e*6+j], aq);
                ak = fmaf(xo[e], Wk2[e*6+j], ak);
                av = fmaf(xo[e], Wv2[e*6+j], av);
            }
            q[(size_t)i*6+j] = aq; k[(size_t)i*6+j] = ak; v[(size_t)i*6+j] = av;
        }
    }
}

// ---------------------------------------------------------------------------
// K5: GI = Y[0:8] @ Wih^T + bih   (Y rows are contiguous slices of x)
// ---------------------------------------------------------------------------
__global__ __launch_bounds__(256) void k_gi(
    const float* __restrict__ x, const float* __restrict__ Wih,
    const float* __restrict__ bih, float* __restrict__ GI)
{
    int bx = blockIdx.x;               // 8 * 144 blocks
    int w  = bx / 144, jb = bx % 144;
    int wave = threadIdx.x >> 6, lane = threadIdx.x & 63;
    int bq = lane >> 4, kg = lane & 15;
    int j0 = jb*16 + wave*4;

    float acc[4][4];                   // [jl][bb]
#pragma unroll
    for (int a = 0; a < 4; ++a)
#pragma unroll
        for (int c = 0; c < 4; ++c) acc[a][c] = 0.f;

#pragma unroll
    for (int c = 0; c < 3; ++c) {      // k chunks of 16 (total 48 per lane)
        float4 wv[4][4];
#pragma unroll
        for (int jl = 0; jl < 4; ++jl) {
            const float4* wp = (const float4*)(Wih + (size_t)(j0+jl)*768 + kg*48 + c*16);
#pragma unroll
            for (int t = 0; t < 4; ++t) wv[jl][t] = wp[t];
        }
#pragma unroll
        for (int bb = 0; bb < 4; ++bb) {
            int b = bq*4 + bb;
            const float4* hp = (const float4*)(x + (size_t)(b*Sn + w*Fn)*6 + kg*48 + c*16);
#pragma unroll
            for (int t = 0; t < 4; ++t) {
                float4 hv = hp[t];
#pragma unroll
                for (int jl = 0; jl < 4; ++jl) {
                    acc[jl][bb] = fmaf(hv.x, wv[jl][t].x, acc[jl][bb]);
                    acc[jl][bb] = fmaf(hv.y, wv[jl][t].y, acc[jl][bb]);
                    acc[jl][bb] = fmaf(hv.z, wv[jl][t].z, acc[jl][bb]);
                    acc[jl][bb] = fmaf(hv.w, wv[jl][t].w, acc[jl][bb]);
                }
            }
        }
    }
#pragma unroll
    for (int m = 1; m <= 8; m <<= 1)
#pragma unroll
        for (int jl = 0; jl < 4; ++jl)
#pragma unroll
            for (int bb = 0; bb < 4; ++bb)
                acc[jl][bb] += __shfl_xor(acc[jl][bb], m);
    if (kg == 0) {
#pragma unroll
        for (int jl = 0; jl < 4; ++jl) {
            float bi = bih[j0+jl];
#pragma unroll
            for (int bb = 0; bb < 4; ++bb) {
                int b = bq*4 + bb;
                GI[((size_t)(w*16 + b))*2304 + j0 + jl] = acc[jl][bb] + bi;
            }
        }
    }
}

// ---------------------------------------------------------------------------
// K6: one GRU step: gh = h@Whh^T (+bhh), gates, h_new. block=3 waves (r,z,n),
// each wave 2 n-columns x 16 batch; gate fusion via tiny LDS exchange
// ---------------------------------------------------------------------------
__global__ __launch_bounds__(192) void k_gru(
    const float* __restrict__ hprev, const float* __restrict__ GIw,
    const float* __restrict__ Whh, const float* __restrict__ bhh,
    float* __restrict__ hnew)
{
    __shared__ float ghs[3][2][16];
    int g = threadIdx.x >> 6, lane = threadIdx.x & 63;
    int bq = lane >> 4, kg = lane & 15;
    int n0 = blockIdx.x * 2;

    float acc[2][4];
#pragma unroll
    for (int a = 0; a < 2; ++a)
#pragma unroll
        for (int c = 0; c < 4; ++c) acc[a][c] = 0.f;

#pragma unroll
    for (int c = 0; c < 3; ++c) {
        float4 w0[4], w1[4];
        const float4* wp0 = (const float4*)(Whh + (size_t)(g*768 + n0)*768 + kg*48 + c*16);
        const float4* wp1 = (const float4*)(Whh + (size_t)(g*768 + n0 + 1)*768 + kg*48 + c*16);
#pragma unroll
        for (int t = 0; t < 4; ++t) { w0[t] = wp0[t]; w1[t] = wp1[t]; }
#pragma unroll
        for (int bb = 0; bb < 4; ++bb) {
            int b = bq*4 + bb;
            const float4* hp = (const float4*)(hprev + (size_t)b*768 + kg*48 + c*16);
#pragma unroll
            for (int t = 0; t < 4; ++t) {
                float4 hv = hp[t];
                acc[0][bb] = fmaf(hv.x, w0[t].x, acc[0][bb]);
                acc[0][bb] = fmaf(hv.y, w0[t].y, acc[0][bb]);
                acc[0][bb] = fmaf(hv.z, w0[t].z, acc[0][bb]);
                acc[0][bb] = fmaf(hv.w, w0[t].w, acc[0][bb]);
                acc[1][bb] = fmaf(hv.x, w1[t].x, acc[1][bb]);
                acc[1][bb] = fmaf(hv.y, w1[t].y, acc[1][bb]);
                acc[1][bb] = fmaf(hv.z, w1[t].z, acc[1][bb]);
                acc[1][bb] = fmaf(hv.w, w1[t].w, acc[1][bb]);
            }
        }
    }
#pragma unroll
    for (int m = 1; m <= 8; m <<= 1)
#pragma unroll
        for (int jl = 0; jl < 2; ++jl)
#pragma unroll
            for (int bb = 0; bb < 4; ++bb)
                acc[jl][bb] += __shfl_xor(acc[jl][bb], m);
    if (kg == 0) {
#pragma unroll
        for (int jl = 0; jl < 2; ++jl)
#pragma unroll
            for (int bb = 0; bb < 4; ++bb)
                ghs[g][jl][bq*4+bb] = acc[jl][bb];
    }
    __syncthreads();
    if (threadIdx.x < 32) {
        int b = threadIdx.x & 15, jl = threadIdx.x >> 4;
        int n = n0 + jl;
        float ghr = ghs[0][jl][b] + bhh[n];
        float ghz = ghs[1][jl][b] + bhh[768+n];
        float ghn = ghs[2][jl][b] + bhh[1536+n];
        const float* gib = GIw + (size_t)b*2304;
        float rr = sigmoidf_(gib[n] + ghr);
        float zz = sigmoidf_(gib[768+n] + ghz);
        float nn = tanhf(gib[1536+n] + rr*ghn);
        hnew[(size_t)b*768 + n] = fmaf(-zz, nn, nn) + zz*hprev[(size_t)b*768 + n];
    }
}

// ---------------------------------------------------------------------------
// K7: out = sigmoid(h @ fcn_W + fcn_b)
// ---------------------------------------------------------------------------
__global__ __launch_bounds__(128) void k_final(
    const float* __restrict__ h, const float* __restrict__ fW,
    const float* __restrict__ fb, float* __restrict__ out)
{
    __shared__ float hs[768];
    int b = blockIdx.x, f = threadIdx.x;
    for (int i = threadIdx.x; i < 768; i += 128) hs[i] = h[(size_t)b*768 + i];
    __syncthreads();
    float a0 = fb[f], a1 = 0.f, a2 = 0.f, a3 = 0.f;
#pragma unroll 4
    for (int k = 0; k < 768; k += 4) {
        a0 = fmaf(hs[k+0], fW[(size_t)(k+0)*128 + f], a0);
        a1 = fmaf(hs[k+1], fW[(size_t)(k+1)*128 + f], a1);
        a2 = fmaf(hs[k+2], fW[(size_t)(k+2)*128 + f], a2);
        a3 = fmaf(hs[k+3], fW[(size_t)(k+3)*128 + f], a3);
    }
    out[(size_t)b*128 + f] = sigmoidf_((a0+a1)+(a2+a3));
}

// ---------------------------------------------------------------------------
extern "C" void kernel_launch(void* const* d_in, const int* in_sizes, int n_in,
                              void* d_out, int out_size, void* d_ws, size_t ws_size,
                              hipStream_t stream)
{
    const float* src   = (const float*)d_in[0];
    const float* w1w   = (const float*)d_in[1];
    const float* w1b   = (const float*)d_in[2];
    const float* w2w   = (const float*)d_in[3];
    const float* w2b   = (const float*)d_in[4];
    const float* meta  = (const float*)d_in[5];
    const float* pos   = (const float*)d_in[6];
    const float* Wq    = (const float*)d_in[7];
    const float* Wk    = (const float*)d_in[8];
    const float* Wv    = (const float*)d_in[9];
    const float* Wo    = (const float*)d_in[10];
    const float* bq    = (const float*)d_in[11];
    const float* bk    = (const float*)d_in[12];
    const float* bv    = (const float*)d_in[13];
    const float* bo    = (const float*)d_in[14];
    const float* l1s   = (const float*)d_in[15];
    const float* l1b   = (const float*)d_in[16];
    const float* W1    = (const float*)d_in[17];
    const float* b1    = (const float*)d_in[18];
    const float* W2    = (const float*)d_in[19];
    const float* b2    = (const float*)d_in[20];
    const float* l2s   = (const float*)d_in[21];
    const float* l2b   = (const float*)d_in[22];
    const float* Wih   = (const float*)d_in[23];
    const float* Whh   = (const float*)d_in[24];
    const float* bih   = (const float*)d_in[25];
    const float* bhh   = (const float*)d_in[26];
    const float* hini  = (const float*)d_in[27];
    const float* fW    = (const float*)d_in[28];
    const float* fb    = (const float*)d_in[29];

    float* ws = (float*)d_ws;
    float* x  = ws;                 // 110592
    float* q  = x  + 110592;
    float* k  = q  + 110592;
    float* v  = k  + 110592;
    float* o  = v  + 110592;
    float* GI = o  + 110592;        // 294912
    float* h0 = GI + 294912;        // 12288
    float* h1 = h0 + 12288;

    k_autodis_qkv<<<72, 256, 0, stream>>>(src, w1w, w1b, w2w, w2b, meta, pos,
                                          Wq, Wk, Wv, bq, bk, bv, x, q, k, v);

    for (int l = 0; l < NLn; ++l) {
        k_attn<<<Bn*NHn*72, 256, 0, stream>>>(q, k, v, o);
        bool nx = (l + 1 < NLn);
        k_post<<<72, 256, 0, stream>>>(x, o, Wo + l*36, bo + l*6,
                                       l1s + l*6, l1b + l*6,
                                       W1 + l*72, b1 + l*12,
                                       W2 + l*72, b2 + l*6,
                                       l2s + l*6, l2b + l*6, x,
                                       nx ? Wq + (l+1)*36 : nullptr,
                                       nx ? Wk + (l+1)*36 : nullptr,
                                       nx ? Wv + (l+1)*36 : nullptr,
                                       nx ? bq + (l+1)*6  : nullptr,
                                       nx ? bk + (l+1)*6  : nullptr,
                                       nx ? bv + (l+1)*6  : nullptr,
                                       q, k, v);
    }

    k_gi<<<8*144, 256, 0, stream>>>(x, Wih, bih, GI);

    const float* hcur = hini;
    float* hb[2] = {h0, h1};
    for (int w = 0; w < 8; ++w) {
        float* hn = hb[w & 1];
        k_gru<<<384, 192, 0, stream>>>(hcur, GI + (size_t)w*16*2304, Whh, bhh, hn);
        hcur = hn;
    }

    k_final<<<16, 128, 0, stream>>>(hcur, fW, fb, (float*)d_out);
}

// Round 14
// 444.985 us; speedup vs baseline: 1.0167x; 1.0167x over previous
//
#include <hip/hip_runtime.h>
#include <hip/hip_bf16.h>
#include <math.h>

// Problem constants
#define Fn   128
#define Wn   9
#define Bn   16
#define En   6
#define NHn  3
#define NLn  3
#define FFDn 12
#define HIDn 768       // F*E
#define Sn   1152      // W*F
#define TOPMn 99
#define DHn  2

__device__ __forceinline__ float sigmoidf_(float x) {
    return 1.0f / (1.0f + __expf(-x));
}

// order-preserving float<->uint key mapping (total order)
__device__ __forceinline__ unsigned f2k(float f) {
    unsigned b = __float_as_uint(f);
    return (b & 0x80000000u) ? ~b : (b | 0x80000000u);
}
__device__ __forceinline__ float k2f(unsigned k) {
    return __uint_as_float((k & 0x80000000u) ? (k & 0x7FFFFFFFu) : ~k);
}

// ---------------------------------------------------------------------------
// K1: AutoDis + positional embedding -> x [B,S,E], fused layer-0 QKV
// (144 blocks x 128 threads: better CU spread for this latency-bound kernel)
// ---------------------------------------------------------------------------
__global__ __launch_bounds__(128) void k_autodis_qkv(
    const float* __restrict__ src, const float* __restrict__ w1w,
    const float* __restrict__ w1b, const float* __restrict__ w2w,
    const float* __restrict__ w2b, const float* __restrict__ meta,
    const float* __restrict__ pos, const float* __restrict__ Wq,
    const float* __restrict__ Wk, const float* __restrict__ Wv,
    const float* __restrict__ bq, const float* __restrict__ bk,
    const float* __restrict__ bv,
    float* __restrict__ x, float* __restrict__ q,
    float* __restrict__ k, float* __restrict__ v)
{
    int i = blockIdx.x * 128 + threadIdx.x;   // over W*B*F = 18432
    if (i >= Wn * Bn * Fn) return;
    int f = i & 127;
    int b = (i >> 7) & 15;
    int w = i >> 11;

    float s = src[i];
    float h1[6];
#pragma unroll
    for (int j = 0; j < 6; ++j) {
        float t = fmaf(s, w1w[f*6+j], w1b[f*6+j]);
        h1[j] = t >= 0.f ? t : 0.01f * t;          // LeakyReLU 0.01
    }
    float tt[6];
    float mx = -3.0e38f;
#pragma unroll
    for (int j = 0; j < 6; ++j) {
        float a = w2b[f*6+j];
#pragma unroll
        for (int kk = 0; kk < 6; ++kk) a = fmaf(h1[kk], w2w[(f*6+kk)*6+j], a);
        a = fmaf(0.5f, h1[j], a);                  // + CTRL*h1
        tt[j] = a;
        mx = fmaxf(mx, a);
    }
    float e[6], sum = 0.f;
#pragma unroll
    for (int j = 0; j < 6; ++j) { e[j] = __expf((tt[j]-mx) * 1e5f); sum += e[j]; }
    float isum = 1.f / sum;
    int srow = w*Fn + f;
    size_t row = (size_t)(b*Sn + srow);
    float xr[6];
#pragma unroll
    for (int ee = 0; ee < 6; ++ee) {
        float a = 0.f;
#pragma unroll
        for (int kk = 0; kk < 6; ++kk) a = fmaf(e[kk], meta[(f*6+kk)*6+ee], a);
        xr[ee] = fmaf(a * isum, 2.449489742783178f, pos[srow*6+ee]);
        x[row*6 + ee] = xr[ee];
    }
    // layer-0 QKV
#pragma unroll
    for (int j = 0; j < 6; ++j) {
        float aq = bq[j], ak = bk[j], av = bv[j];
#pragma unroll
        for (int ee = 0; ee < 6; ++ee) {
            aq = fmaf(xr[ee], Wq[ee*6+j], aq);
            ak = fmaf(xr[ee], Wk[ee*6+j], ak);
            av = fmaf(xr[ee], Wv[ee*6+j], av);
        }
        q[row*6+j] = aq; k[row*6+j] = ak; v[row*6+j] = av;
    }
}

// ---------------------------------------------------------------------------
// K3: fused attention (R12-verified structure: 72 chunks of 16 rows, 4 rows
// per wave sequentially, K and V staged in LDS). Exact top-99 threshold:
//  A: 2 statistical seed probes (count-only); cnt==99 -> DONE (the mask
//     {s>=t} with count exactly 99 IS the top-99 set -- identical softmax)
//  B: data-pivot probes while cl-ch>128 (tie-immune; key-midpoint every
//     4th as worst-case bound); same cnt==99 exit
//  C: compact <=128 candidates to 2/lane; ballot quickselect (pivot always
//     a live value -> |active| strictly decreases; == branch -> thr==s_99)
// Exactness: cl=cnt(>=flo)>=99>ch=cnt(>=fhi) with exact ballot counts;
// [flo,fhi) contains rank 99; the selected SET always equals jax's
// {s >= top_k[..,-1]} incl. ties.
// ---------------------------------------------------------------------------
__global__ __launch_bounds__(256) void k_attn(
    const float* __restrict__ q, const float* __restrict__ kbuf,
    const float* __restrict__ vbuf, float* __restrict__ o)
{
    __shared__ float2 Ks[Sn];
    __shared__ float2 Vs[Sn];
    __shared__ float cbuf[4][128];
    int bx = blockIdx.x;
    int qc = bx % 72;              // 72 q-chunks of 16 rows
    int bh = bx / 72;
    int h = bh % NHn, b = bh / NHn;
    int lane = threadIdx.x & 63, wave = threadIdx.x >> 6;

    for (int idx = threadIdx.x; idx < Sn; idx += 256) {
        Ks[idx] = *(const float2*)(kbuf + ((size_t)(b*Sn + idx))*6 + h*2);
        Vs[idx] = *(const float2*)(vbuf + ((size_t)(b*Sn + idx))*6 + h*2);
    }
    __syncthreads();

    const float scale = 0.70710678118654752f;  // 1/sqrt(DH)
#pragma unroll 1
    for (int r = 0; r < 4; ++r) {
        int qrow = qc*16 + wave*4 + r;
        const float* qp = q + ((size_t)(b*Sn + qrow))*6 + h*2;
        float qx = qp[0]*scale, qy = qp[1]*scale;

        float sc[18];
        float mx = -3.0e38f, s1 = 0.f, s2 = 0.f;
#pragma unroll
        for (int j = 0; j < 18; ++j) {
            float2 kk = Ks[lane + 64*j];
            float s = fmaf(qx, kk.x, qy*kk.y);
            sc[j] = s;
            mx = fmaxf(mx, s);
            s1 += s; s2 = fmaf(s, s, s2);
        }
        for (int off = 32; off; off >>= 1) {
            mx = fmaxf(mx, __shfl_xor(mx, off));
            s1 += __shfl_xor(s1, off);
            s2 += __shfl_xor(s2, off);
        }
        mx = __uint_as_float(__builtin_amdgcn_readfirstlane(__float_as_uint(mx)));
        s1 = __uint_as_float(__builtin_amdgcn_readfirstlane(__float_as_uint(s1)));
        s2 = __uint_as_float(__builtin_amdgcn_readfirstlane(__float_as_uint(s2)));

        const float invN = 1.0f/1152.0f;
        float mu = s1*invN;
        float sg = sqrtf(fmaxf(fmaf(-mu, mu, s2*invN), 0.f) + 1e-20f);

        float flo = -3.0e38f;                  // cnt(>=flo) = 1152
        float fhi = k2f(f2k(mx) + 1u);         // cnt(>=fhi) = 0
        int cl = 1152, ch = 0;
        float thr = flo;
        bool resolved = false;
        float lastf = 0.f; int lastc = 0;

        // ---- Phase A: 2 seed probes (cnt==99 -> done) ----
#pragma unroll 1
        for (int s = 0; s < 2; ++s) {
            unsigned klo = f2k(flo), khi = f2k(fhi);
            if (khi - klo <= 1u) break;
            float t = (s == 0) ? fmaf(1.366f, sg, mu)
                               : fmaf((float)(lastc - 99)*0.005543f, sg, lastf);
            unsigned tk = f2k(t);
            if (tk <= klo) tk = klo + 1u; else if (tk >= khi) tk = khi - 1u;
            t = k2f(tk);
            int cnt = 0;
#pragma unroll
            for (int j = 0; j < 18; ++j)
                cnt += (int)__popcll(__ballot(sc[j] >= t));
            if (cnt == 99) { thr = t; resolved = true; break; }  // exact set
            if (cnt > 99) { flo = t; cl = cnt; } else { fhi = t; ch = cnt; }
            lastf = t; lastc = cnt;
        }

        // ---- Phase B: data-pivot probes (key-midpoint every 4th) ----
        if (!resolved) {
#pragma unroll 1
            for (int it = 0; it < 200 && (cl - ch) > 128; ++it) {
                float cval = 0.f; bool have = false;
#pragma unroll
                for (int j = 0; j < 18; ++j) {
                    bool c = (sc[j] > flo) && (sc[j] < fhi);
                    cval = c ? sc[j] : cval;
                    have = have || c;
                }
                unsigned long long m = __ballot(have);
                if (m == 0ull) { thr = flo; resolved = true; break; }
                float t;
                if ((it & 3) == 3) {               // key-space midpoint safety
                    unsigned klo = f2k(flo), khi = f2k(fhi);
                    unsigned tk = klo + ((khi - klo) >> 1);
                    if (tk <= klo) tk = klo + 1u;
                    if (tk >= khi) tk = khi - 1u;
                    t = k2f(tk);
                } else {                           // data pivot (rotating lane)
                    unsigned rr = (unsigned)(it * 23) & 63u;
                    unsigned long long rot =
                        rr ? ((m >> rr) | (m << (64u - rr))) : m;
                    int lsel = (__builtin_ctzll(rot) + (int)rr) & 63;
                    t = __shfl(cval, lsel);
                }
                int cnt = 0;
#pragma unroll
                for (int j = 0; j < 18; ++j)
                    cnt += (int)__popcll(__ballot(sc[j] >= t));
                if (cnt == 99) { thr = t; resolved = true; break; }  // exact set
                if (cnt > 99) { flo = t; cl = cnt; } else { fhi = t; ch = cnt; }
            }
        }

        if (!resolved) {
            // ---- Phase C: compact candidates [flo,fhi) -> 2/lane ----
            int ncand = cl - ch;               // 1..128 guaranteed here
            int myn = 0;
#pragma unroll
            for (int j = 0; j < 18; ++j)
                myn += ((sc[j] >= flo) && (sc[j] < fhi)) ? 1 : 0;
            int pre = myn;
#pragma unroll
            for (int d = 1; d < 64; d <<= 1) {
                int t2 = __shfl_up(pre, d);
                if (lane >= d) pre += t2;
            }
            pre -= myn;                        // exclusive prefix
            int idx = pre;
#pragma unroll
            for (int j = 0; j < 18; ++j) {
                if ((sc[j] >= flo) && (sc[j] < fhi)) {
                    if (idx < 128) cbuf[wave][idx] = sc[j];
                    ++idx;
                }
            }
            __builtin_amdgcn_wave_barrier();
            float v0 = (lane < ncand)      ? cbuf[wave][lane]      : 0.f;
            float v1 = (lane + 64 < ncand) ? cbuf[wave][lane + 64] : 0.f;
            unsigned long long a0 = __ballot(lane < ncand);
            unsigned long long a1 = __ballot(lane + 64 < ncand);
            int kp = 99 - ch;                  // 1..ncand
#pragma unroll 1
            for (int it = 0; it < 200; ++it) {
                bool useA = (a0 != 0ull);
                unsigned long long m = useA ? a0 : a1;
                unsigned rr = (unsigned)(it * 23) & 63u;
                unsigned long long rot =
                    rr ? ((m >> rr) | (m << (64u - rr))) : m;
                int lsel = (__builtin_ctzll(rot) + (int)rr) & 63;
                float piv = useA ? __shfl(v0, lsel) : __shfl(v1, lsel);
                unsigned long long bgt0 = __ballot(v0 > piv) & a0;
                unsigned long long bgt1 = __ballot(v1 > piv) & a1;
                unsigned long long beq0 = __ballot(v0 == piv) & a0;
                unsigned long long beq1 = __ballot(v1 == piv) & a1;
                int cgt = (int)__popcll(bgt0) + (int)__popcll(bgt1);
                int ceq = (int)__popcll(beq0) + (int)__popcll(beq1);
                if (kp <= cgt) { a0 = bgt0; a1 = bgt1; }
                else if (kp <= cgt + ceq) { thr = piv; break; }
                else {
                    kp -= cgt + ceq;
                    a0 &= __ballot(v0 < piv);
                    a1 &= __ballot(v1 < piv);
                }
            }
        }

        float psum = 0.f, ox = 0.f, oy = 0.f;
#pragma unroll
        for (int j = 0; j < 18; ++j) {
            float p = (sc[j] >= thr) ? __expf(sc[j] - mx) : 0.f;
            psum += p;
            float2 vv = Vs[lane + 64*j];
            ox = fmaf(p, vv.x, ox);
            oy = fmaf(p, vv.y, oy);
        }
        for (int off = 32; off; off >>= 1) {
            psum += __shfl_xor(psum, off);
            ox   += __shfl_xor(ox, off);
            oy   += __shfl_xor(oy, off);
        }
        if (lane == 0) {
            float inv = 1.f / psum;
            float* op = o + ((size_t)(b*Sn + qrow))*6 + h*2;
            op[0] = ox*inv; op[1] = oy*inv;
        }
    }
}

// ---------------------------------------------------------------------------
// K4: o@Wo + residual + LN1 + FFN + residual + LN2 (+ optional next-layer QKV)
// (144 blocks x 128 threads)
// ---------------------------------------------------------------------------
__global__ __launch_bounds__(128) void k_post(
    const float* __restrict__ xin, const float* __restrict__ ob,
    const float* __restrict__ Wo, const float* __restrict__ bo,
    const float* __restrict__ l1s, const float* __restrict__ l1b,
    const float* __restrict__ W1, const float* __restrict__ b1,
    const float* __restrict__ W2, const float* __restrict__ b2,
    const float* __restrict__ l2s, const float* __restrict__ l2b,
    float* __restrict__ xout,
    const float* __restrict__ Wq2, const float* __restrict__ Wk2,
    const float* __restrict__ Wv2, const float* __restrict__ bq2,
    const float* __restrict__ bk2, const float* __restrict__ bv2,
    float* __restrict__ q, float* __restrict__ k, float* __restrict__ v)
{
    int i = blockIdx.x * 128 + threadIdx.x;
    if (i >= Bn * Sn) return;
    float xr[6], orow[6];
#pragma unroll
    for (int e = 0; e < 6; ++e) {
        xr[e]   = xin[(size_t)i*6 + e];
        orow[e] = ob[(size_t)i*6 + e];
    }
    float rbuf[6];
#pragma unroll
    for (int j = 0; j < 6; ++j) {
        float a = bo[j];
#pragma unroll
        for (int e = 0; e < 6; ++e) a = fmaf(orow[e], Wo[e*6+j], a);
        rbuf[j] = xr[j] + a;
    }
    // LN1
    float mean = 0.f;
#pragma unroll
    for (int j = 0; j < 6; ++j) mean += rbuf[j];
    mean *= (1.f/6.f);
    float var = 0.f;
#pragma unroll
    for (int j = 0; j < 6; ++j) { float d = rbuf[j]-mean; var = fmaf(d, d, var); }
    var *= (1.f/6.f);
    float inv = rsqrtf(var + 1e-5f);
    float y1[6];
#pragma unroll
    for (int j = 0; j < 6; ++j) y1[j] = fmaf((rbuf[j]-mean)*inv, l1s[j], l1b[j]);
    // FFN
    float ff[12];
#pragma unroll
    for (int jj = 0; jj < 12; ++jj) {
        float a = b1[jj];
#pragma unroll
        for (int e = 0; e < 6; ++e) a = fmaf(y1[e], W1[e*12+jj], a);
        ff[jj] = fmaxf(a, 0.f);
    }
#pragma unroll
    for (int j = 0; j < 6; ++j) {
        float a = b2[j];
#pragma unroll
        for (int kk = 0; kk < 12; ++kk) a = fmaf(ff[kk], W2[kk*6+j], a);
        rbuf[j] = y1[j] + a;
    }
    // LN2
    mean = 0.f;
#pragma unroll
    for (int j = 0; j < 6; ++j) mean += rbuf[j];
    mean *= (1.f/6.f);
    var = 0.f;
#pragma unroll
    for (int j = 0; j < 6; ++j) { float d = rbuf[j]-mean; var = fmaf(d, d, var); }
    var *= (1.f/6.f);
    inv = rsqrtf(var + 1e-5f);
    float xo[6];
#pragma unroll
    for (int j = 0; j < 6; ++j) {
        xo[j] = fmaf((rbuf[j]-mean)*inv, l2s[j], l2b[j]);
        xout[(size_t)i*6 + j] = xo[j];
    }
    if (Wq2) {  // fused next-layer QKV (wave-uniform branch)
#pragma unroll
        for (int j = 0; j < 6; ++j) {
            float aq = bq2[j], ak = bk2[j], av = bv2[j];
#pragma unroll
            for (int e = 0; e < 6; ++e) {
                aq = fmaf(xo[e], Wq2[e*6+j], aq);
                ak = fmaf(xo[e], Wk2[e*6+j], ak);
                av = fmaf(xo[e], Wv2[e*6+j], av);
            }
            q[(size_t)i*6+j] = aq; k[(size_t)i*6+j] = ak; v[(size_t)i*6+j] = av;
        }
    }
}

// ---------------------------------------------------------------------------
// K5: GI = Y[0:8] @ Wih^T + bih   (Y rows are contiguous slices of x)
// ---------------------------------------------------------------------------
__global__ __launch_bounds__(256) void k_gi(
    const float* __restrict__ x, const float* __restrict__ Wih,
    const float* __restrict__ bih, float* __restrict__ GI)
{
    int bx = blockIdx.x;               // 8 * 144 blocks
    int w  = bx / 144, jb = bx % 144;
    int wave = threadIdx.x >> 6, lane = threadIdx.x & 63;
    int bq = lane >> 4, kg = lane & 15;
    int j0 = jb*16 + wave*4;

    float acc[4][4];                   // [jl][bb]
#pragma unroll
    for (int a = 0; a < 4; ++a)
#pragma unroll
        for (int c = 0; c < 4; ++c) acc[a][c] = 0.f;

#pragma unroll
    for (int c = 0; c < 3; ++c) {      // k chunks of 16 (total 48 per lane)
        float4 wv[4][4];
#pragma unroll
        for (int jl = 0; jl < 4; ++jl) {
            const float4* wp = (const float4*)(Wih + (size_t)(j0+jl)*768 + kg*48 + c*16);
#pragma unroll
            for (int t = 0; t < 4; ++t) wv[jl][t] = wp[t];
        }
#pragma unroll
        for (int bb = 0; bb < 4; ++bb) {
            int b = bq*4 + bb;
            const float4* hp = (const float4*)(x + (size_t)(b*Sn + w*Fn)*6 + kg*48 + c*16);
#pragma unroll
            for (int t = 0; t < 4; ++t) {
                float4 hv = hp[t];
#pragma unroll
                for (int jl = 0; jl < 4; ++jl) {
                    acc[jl][bb] = fmaf(hv.x, wv[jl][t].x, acc[jl][bb]);
                    acc[jl][bb] = fmaf(hv.y, wv[jl][t].y, acc[jl][bb]);
                    acc[jl][bb] = fmaf(hv.z, wv[jl][t].z, acc[jl][bb]);
                    acc[jl][bb] = fmaf(hv.w, wv[jl][t].w, acc[jl][bb]);
                }
            }
        }
    }
#pragma unroll
    for (int m = 1; m <= 8; m <<= 1)
#pragma unroll
        for (int jl = 0; jl < 4; ++jl)
#pragma unroll
            for (int bb = 0; bb < 4; ++bb)
                acc[jl][bb] += __shfl_xor(acc[jl][bb], m);
    if (kg == 0) {
#pragma unroll
        for (int jl = 0; jl < 4; ++jl) {
            float bi = bih[j0+jl];
#pragma unroll
            for (int bb = 0; bb < 4; ++bb) {
                int b = bq*4 + bb;
                GI[((size_t)(w*16 + b))*2304 + j0 + jl] = acc[jl][bb] + bi;
            }
        }
    }
}

// ---------------------------------------------------------------------------
// K6: one GRU step: gh = h@Whh^T (+bhh), gates, h_new. block=3 waves (r,z,n),
// each wave 2 n-columns x 16 batch; gate fusion via tiny LDS exchange
// ---------------------------------------------------------------------------
__global__ __launch_bounds__(192) void k_gru(
    const float* __restrict__ hprev, const float* __restrict__ GIw,
    const float* __restrict__ Whh, const float* __restrict__ bhh,
    float* __restrict__ hnew)
{
    __shared__ float ghs[3][2][16];
    int g = threadIdx.x >> 6, lane = threadIdx.x & 63;
    int bq = lane >> 4, kg = lane & 15;
    int n0 = blockIdx.x * 2;

    float acc[2][4];
#pragma unroll
    for (int a = 0; a < 2; ++a)
#pragma unroll
        for (int c = 0; c < 4; ++c) acc[a][c] = 0.f;

#pragma unroll
    for (int c = 0; c < 3; ++c) {
        float4 w0[4], w1[4];
        const float4* wp0 = (const float4*)(Whh + (size_t)(g*768 + n0)*768 + kg*48 + c*16);
        const float4* wp1 = (const float4*)(Whh + (size_t)(g*768 + n0 + 1)*768 + kg*48 + c*16);
#pragma unroll
        for (int t = 0; t < 4; ++t) { w0[t] = wp0[t]; w1[t] = wp1[t]; }
#pragma unroll
        for (int bb = 0; bb < 4; ++bb) {
            int b = bq*4 + bb;
            const float4* hp = (const float4*)(hprev + (size_t)b*768 + kg*48 + c*16);
#pragma unroll
            for (int t = 0; t < 4; ++t) {
                float4 hv = hp[t];
                acc[0][bb] = fmaf(hv.x, w0[t].x, acc[0][bb]);
                acc[0][bb] = fmaf(hv.y, w0[t].y, acc[0][bb]);
                acc[0][bb] = fmaf(hv.z, w0[t].z, acc[0][bb]);
                acc[0][bb] = fmaf(hv.w, w0[t].w, acc[0][bb]);
                acc[1][bb] = fmaf(hv.x, w1[t].x, acc[1][bb]);
                acc[1][bb] = fmaf(hv.y, w1[t].y, acc[1][bb]);
                acc[1][bb] = fmaf(hv.z, w1[t].z, acc[1][bb]);
                acc[1][bb] = fmaf(hv.w, w1[t].w, acc[1][bb]);
            }
        }
    }
#pragma unroll
    for (int m = 1; m <= 8; m <<= 1)
#pragma unroll
        for (int jl = 0; jl < 2; ++jl)
#pragma unroll
            for (int bb = 0; bb < 4; ++bb)
                acc[jl][bb] += __shfl_xor(acc[jl][bb], m);
    if (kg == 0) {
#pragma unroll
        for (int jl = 0; jl < 2; ++jl)
#pragma unroll
            for (int bb = 0; bb < 4; ++bb)
                ghs[g][jl][bq*4+bb] = acc[jl][bb];
    }
    __syncthreads();
    if (threadIdx.x < 32) {
        int b = threadIdx.x & 15, jl = threadIdx.x >> 4;
        int n = n0 + jl;
        float ghr = ghs[0][jl][b] + bhh[n];
        float ghz = ghs[1][jl][b] + bhh[768+n];
        float ghn = ghs[2][jl][b] + bhh[1536+n];
        const float* gib = GIw + (size_t)b*2304;
        float rr = sigmoidf_(gib[n] + ghr);
        float zz = sigmoidf_(gib[768+n] + ghz);
        float nn = tanhf(gib[1536+n] + rr*ghn);
        hnew[(size_t)b*768 + n] = fmaf(-zz, nn, nn) + zz*hprev[(size_t)b*768 + n];
    }
}

// ---------------------------------------------------------------------------
// K7: out = sigmoid(h @ fcn_W + fcn_b)
// ---------------------------------------------------------------------------
__global__ __launch_bounds__(128) void k_final(
    const float* __restrict__ h, const float* __restrict__ fW,
    const float* __restrict__ fb, float* __restrict__ out)
{
    __shared__ float hs[768];
    int b = blockIdx.x, f = threadIdx.x;
    for (int i = threadIdx.x; i < 768; i += 128) hs[i] = h[(size_t)b*768 + i];
    __syncthreads();
    float a0 = fb[f], a1 = 0.f, a2 = 0.f, a3 = 0.f;
#pragma unroll 4
    for (int k = 0; k < 768; k += 4) {
        a0 = fmaf(hs[k+0], fW[(size_t)(k+0)*128 + f], a0);
        a1 = fmaf(hs[k+1], fW[(size_t)(k+1)*128 + f], a1);
        a2 = fmaf(hs[k+2], fW[(size_t)(k+2)*128 + f], a2);
        a3 = fmaf(hs[k+3], fW[(size_t)(k+3)*128 + f], a3);
    }
    out[(size_t)b*128 + f] = sigmoidf_((a0+a1)+(a2+a3));
}

// ---------------------------------------------------------------------------
extern "C" void kernel_launch(void* const* d_in, const int* in_sizes, int n_in,
                              void* d_out, int out_size, void* d_ws, size_t ws_size,
                              hipStream_t stream)
{
    const float* src   = (const float*)d_in[0];
    const float* w1w   = (const float*)d_in[1];
    const float* w1b   = (const float*)d_in[2];
    const float* w2w   = (const float*)d_in[3];
    const float* w2b   = (const float*)d_in[4];
    const float* meta  = (const float*)d_in[5];
    const float* pos   = (const float*)d_in[6];
    const float* Wq    = (const float*)d_in[7];
    const float* Wk    = (const float*)d_in[8];
    const float* Wv    = (const float*)d_in[9];
    const float* Wo    = (const float*)d_in[10];
    const float* bq    = (const float*)d_in[11];
    const float* bk    = (const float*)d_in[12];
    const float* bv    = (const float*)d_in[13];
    const float* bo    = (const float*)d_in[14];
    const float* l1s   = (const float*)d_in[15];
    const float* l1b   = (const float*)d_in[16];
    const float* W1    = (const float*)d_in[17];
    const float* b1    = (const float*)d_in[18];
    const float* W2    = (const float*)d_in[19];
    const float* b2    = (const float*)d_in[20];
    const float* l2s   = (const float*)d_in[21];
    const float* l2b   = (const float*)d_in[22];
    const float* Wih   = (const float*)d_in[23];
    const float* Whh   = (const float*)d_in[24];
    const float* bih   = (const float*)d_in[25];
    const float* bhh   = (const float*)d_in[26];
    const float* hini  = (const float*)d_in[27];
    const float* fW    = (const float*)d_in[28];
    const float* fb    = (const float*)d_in[29];

    float* ws = (float*)d_ws;
    float* x  = ws;                 // 110592
    float* q  = x  + 110592;
    float* k  = q  + 110592;
    float* v  = k  + 110592;
    float* o  = v  + 110592;
    float* GI = o  + 110592;        // 294912
    float* h0 = GI + 294912;        // 12288
    float* h1 = h0 + 12288;

    k_autodis_qkv<<<144, 128, 0, stream>>>(src, w1w, w1b, w2w, w2b, meta, pos,
                                           Wq, Wk, Wv, bq, bk, bv, x, q, k, v);

    for (int l = 0; l < NLn; ++l) {
        k_attn<<<Bn*NHn*72, 256, 0, stream>>>(q, k, v, o);
        bool nx = (l + 1 < NLn);
        k_post<<<144, 128, 0, stream>>>(x, o, Wo + l*36, bo + l*6,
                                        l1s + l*6, l1b + l*6,
                                        W1 + l*72, b1 + l*12,
                                        W2 + l*72, b2 + l*6,
                                        l2s + l*6, l2b + l*6, x,
                                        nx ? Wq + (l+1)*36 : nullptr,
                                        nx ? Wk + (l+1)*36 : nullptr,
                                        nx ? Wv + (l+1)*36 : nullptr,
                                        nx ? bq + (l+1)*6  : nullptr,
                                        nx ? bk + (l+1)*6  : nullptr,
                                        nx ? bv + (l+1)*6  : nullptr,
                                        q, k, v);
    }

    k_gi<<<8*144, 256, 0, stream>>>(x, Wih, bih, GI);

    const float* hcur = hini;
    float* hb[2] = {h0, h1};
    for (int w = 0; w < 8; ++w) {
        float* hn = hb[w & 1];
        k_gru<<<384, 192, 0, stream>>>(hcur, GI + (size_t)w*16*2304, Whh, bhh, hn);
        hcur = hn;
    }

    k_final<<<16, 128, 0, stream>>>(hcur, fW, fb, (float*)d_out);
}

// Round 15
// 440.886 us; speedup vs baseline: 1.0261x; 1.0093x over previous
//
#include <hip/hip_runtime.h>
#include <hip/hip_bf16.h>
#include <math.h>

// Problem constants
#define Fn   128
#define Wn   9
#define Bn   16
#define En   6
#define NHn  3
#define NLn  3
#define FFDn 12
#define HIDn 768       // F*E
#define Sn   1152      // W*F
#define TOPMn 99
#define DHn  2

__device__ __forceinline__ float sigmoidf_(float x) {
    return 1.0f / (1.0f + __expf(-x));
}

// order-preserving float<->uint key mapping (total order)
__device__ __forceinline__ unsigned f2k(float f) {
    unsigned b = __float_as_uint(f);
    return (b & 0x80000000u) ? ~b : (b | 0x80000000u);
}
__device__ __forceinline__ float k2f(unsigned k) {
    return __uint_as_float((k & 0x80000000u) ? (k & 0x7FFFFFFFu) : ~k);
}

// ---------------------------------------------------------------------------
// K1: AutoDis + positional embedding -> x [B,S,E], fused layer-0 QKV
// ---------------------------------------------------------------------------
__global__ __launch_bounds__(128) void k_autodis_qkv(
    const float* __restrict__ src, const float* __restrict__ w1w,
    const float* __restrict__ w1b, const float* __restrict__ w2w,
    const float* __restrict__ w2b, const float* __restrict__ meta,
    const float* __restrict__ pos, const float* __restrict__ Wq,
    const float* __restrict__ Wk, const float* __restrict__ Wv,
    const float* __restrict__ bq, const float* __restrict__ bk,
    const float* __restrict__ bv,
    float* __restrict__ x, float* __restrict__ q,
    float* __restrict__ k, float* __restrict__ v)
{
    int i = blockIdx.x * 128 + threadIdx.x;   // over W*B*F = 18432
    if (i >= Wn * Bn * Fn) return;
    int f = i & 127;
    int b = (i >> 7) & 15;
    int w = i >> 11;

    float s = src[i];
    float h1[6];
#pragma unroll
    for (int j = 0; j < 6; ++j) {
        float t = fmaf(s, w1w[f*6+j], w1b[f*6+j]);
        h1[j] = t >= 0.f ? t : 0.01f * t;          // LeakyReLU 0.01
    }
    float tt[6];
    float mx = -3.0e38f;
#pragma unroll
    for (int j = 0; j < 6; ++j) {
        float a = w2b[f*6+j];
#pragma unroll
        for (int kk = 0; kk < 6; ++kk) a = fmaf(h1[kk], w2w[(f*6+kk)*6+j], a);
        a = fmaf(0.5f, h1[j], a);                  // + CTRL*h1
        tt[j] = a;
        mx = fmaxf(mx, a);
    }
    float e[6], sum = 0.f;
#pragma unroll
    for (int j = 0; j < 6; ++j) { e[j] = __expf((tt[j]-mx) * 1e5f); sum += e[j]; }
    float isum = 1.f / sum;
    int srow = w*Fn + f;
    size_t row = (size_t)(b*Sn + srow);
    float xr[6];
#pragma unroll
    for (int ee = 0; ee < 6; ++ee) {
        float a = 0.f;
#pragma unroll
        for (int kk = 0; kk < 6; ++kk) a = fmaf(e[kk], meta[(f*6+kk)*6+ee], a);
        xr[ee] = fmaf(a * isum, 2.449489742783178f, pos[srow*6+ee]);
        x[row*6 + ee] = xr[ee];
    }
    // layer-0 QKV
#pragma unroll
    for (int j = 0; j < 6; ++j) {
        float aq = bq[j], ak = bk[j], av = bv[j];
#pragma unroll
        for (int ee = 0; ee < 6; ++ee) {
            aq = fmaf(xr[ee], Wq[ee*6+j], aq);
            ak = fmaf(xr[ee], Wk[ee*6+j], ak);
            av = fmaf(xr[ee], Wv[ee*6+j], av);
        }
        q[row*6+j] = aq; k[row*6+j] = ak; v[row*6+j] = av;
    }
}

// ---------------------------------------------------------------------------
// K3: fused attention. R14-verified search; NEW geometry: 1024-thread block
// = 16 waves, ONE row per wave (was 4 waves x 4 sequential rows). Same grid
// (3456), same 16-rows-per-block K/V staging amortization, same per-row
// search/PV code. Serial chain per wave shrinks 4x; wave count x4 gives the
// scheduler more latency-hiding contexts; 2 blocks x 16 waves = 32 waves/CU
// possible (LDS 26.6KB/block).
// Exact top-99 threshold (verified R12/R14 semantics):
//  A: 2 seed probes (cnt==99 -> exact set, done)
//  B: data-pivot probes while cl-ch>128 (cnt==99 exit; key-midpoint /4th)
//  C: compact <=128 candidates to 2/lane; ballot quickselect.
// Exactness: cl=cnt(>=flo)>=99>ch=cnt(>=fhi) with exact ballot counts;
// selected SET always equals jax's {s >= top_k[..,-1]} incl. ties.
// ---------------------------------------------------------------------------
__global__ __launch_bounds__(1024) void k_attn(
    const float* __restrict__ q, const float* __restrict__ kbuf,
    const float* __restrict__ vbuf, float* __restrict__ o)
{
    __shared__ float2 Ks[Sn];
    __shared__ float2 Vs[Sn];
    __shared__ float cbuf[16][128];
    int bx = blockIdx.x;
    int qc = bx % 72;              // 72 q-chunks of 16 rows
    int bh = bx / 72;
    int h = bh % NHn, b = bh / NHn;
    int lane = threadIdx.x & 63, wave = threadIdx.x >> 6;   // wave 0..15

    for (int idx = threadIdx.x; idx < Sn; idx += 1024) {
        Ks[idx] = *(const float2*)(kbuf + ((size_t)(b*Sn + idx))*6 + h*2);
        Vs[idx] = *(const float2*)(vbuf + ((size_t)(b*Sn + idx))*6 + h*2);
    }
    __syncthreads();

    const float scale = 0.70710678118654752f;  // 1/sqrt(DH)
    {
        int qrow = qc*16 + wave;
        const float* qp = q + ((size_t)(b*Sn + qrow))*6 + h*2;
        float qx = qp[0]*scale, qy = qp[1]*scale;

        float sc[18];
        float mx = -3.0e38f, s1 = 0.f, s2 = 0.f;
#pragma unroll
        for (int j = 0; j < 18; ++j) {
            float2 kk = Ks[lane + 64*j];
            float s = fmaf(qx, kk.x, qy*kk.y);
            sc[j] = s;
            mx = fmaxf(mx, s);
            s1 += s; s2 = fmaf(s, s, s2);
        }
        for (int off = 32; off; off >>= 1) {
            mx = fmaxf(mx, __shfl_xor(mx, off));
            s1 += __shfl_xor(s1, off);
            s2 += __shfl_xor(s2, off);
        }
        mx = __uint_as_float(__builtin_amdgcn_readfirstlane(__float_as_uint(mx)));
        s1 = __uint_as_float(__builtin_amdgcn_readfirstlane(__float_as_uint(s1)));
        s2 = __uint_as_float(__builtin_amdgcn_readfirstlane(__float_as_uint(s2)));

        const float invN = 1.0f/1152.0f;
        float mu = s1*invN;
        float sg = sqrtf(fmaxf(fmaf(-mu, mu, s2*invN), 0.f) + 1e-20f);

        float flo = -3.0e38f;                  // cnt(>=flo) = 1152
        float fhi = k2f(f2k(mx) + 1u);         // cnt(>=fhi) = 0
        int cl = 1152, ch = 0;
        float thr = flo;
        bool resolved = false;
        float lastf = 0.f; int lastc = 0;

        // ---- Phase A: 2 seed probes (cnt==99 -> done) ----
#pragma unroll 1
        for (int s = 0; s < 2; ++s) {
            unsigned klo = f2k(flo), khi = f2k(fhi);
            if (khi - klo <= 1u) break;
            float t = (s == 0) ? fmaf(1.366f, sg, mu)
                               : fmaf((float)(lastc - 99)*0.005543f, sg, lastf);
            unsigned tk = f2k(t);
            if (tk <= klo) tk = klo + 1u; else if (tk >= khi) tk = khi - 1u;
            t = k2f(tk);
            int cnt = 0;
#pragma unroll
            for (int j = 0; j < 18; ++j)
                cnt += (int)__popcll(__ballot(sc[j] >= t));
            if (cnt == 99) { thr = t; resolved = true; break; }  // exact set
            if (cnt > 99) { flo = t; cl = cnt; } else { fhi = t; ch = cnt; }
            lastf = t; lastc = cnt;
        }

        // ---- Phase B: data-pivot probes (key-midpoint every 4th) ----
        if (!resolved) {
#pragma unroll 1
            for (int it = 0; it < 200 && (cl - ch) > 128; ++it) {
                float cval = 0.f; bool have = false;
#pragma unroll
                for (int j = 0; j < 18; ++j) {
                    bool c = (sc[j] > flo) && (sc[j] < fhi);
                    cval = c ? sc[j] : cval;
                    have = have || c;
                }
                unsigned long long m = __ballot(have);
                if (m == 0ull) { thr = flo; resolved = true; break; }
                float t;
                if ((it & 3) == 3) {               // key-space midpoint safety
                    unsigned klo = f2k(flo), khi = f2k(fhi);
                    unsigned tk = klo + ((khi - klo) >> 1);
                    if (tk <= klo) tk = klo + 1u;
                    if (tk >= khi) tk = khi - 1u;
                    t = k2f(tk);
                } else {                           // data pivot (rotating lane)
                    unsigned rr = (unsigned)(it * 23) & 63u;
                    unsigned long long rot =
                        rr ? ((m >> rr) | (m << (64u - rr))) : m;
                    int lsel = (__builtin_ctzll(rot) + (int)rr) & 63;
                    t = __shfl(cval, lsel);
                }
                int cnt = 0;
#pragma unroll
                for (int j = 0; j < 18; ++j)
                    cnt += (int)__popcll(__ballot(sc[j] >= t));
                if (cnt == 99) { thr = t; resolved = true; break; }  // exact set
                if (cnt > 99) { flo = t; cl = cnt; } else { fhi = t; ch = cnt; }
            }
        }

        if (!resolved) {
            // ---- Phase C: compact candidates [flo,fhi) -> 2/lane ----
            int ncand = cl - ch;               // 1..128 guaranteed here
            int myn = 0;
#pragma unroll
            for (int j = 0; j < 18; ++j)
                myn += ((sc[j] >= flo) && (sc[j] < fhi)) ? 1 : 0;
            int pre = myn;
#pragma unroll
            for (int d = 1; d < 64; d <<= 1) {
                int t2 = __shfl_up(pre, d);
                if (lane >= d) pre += t2;
            }
            pre -= myn;                        // exclusive prefix
            int idx = pre;
#pragma unroll
            for (int j = 0; j < 18; ++j) {
                if ((sc[j] >= flo) && (sc[j] < fhi)) {
                    if (idx < 128) cbuf[wave][idx] = sc[j];
                    ++idx;
                }
            }
            __builtin_amdgcn_wave_barrier();
            float v0 = (lane < ncand)      ? cbuf[wave][lane]      : 0.f;
            float v1 = (lane + 64 < ncand) ? cbuf[wave][lane + 64] : 0.f;
            unsigned long long a0 = __ballot(lane < ncand);
            unsigned long long a1 = __ballot(lane + 64 < ncand);
            int kp = 99 - ch;                  // 1..ncand
#pragma unroll 1
            for (int it = 0; it < 200; ++it) {
                bool useA = (a0 != 0ull);
                unsigned long long m = useA ? a0 : a1;
                unsigned rr = (unsigned)(it * 23) & 63u;
                unsigned long long rot =
                    rr ? ((m >> rr) | (m << (64u - rr))) : m;
                int lsel = (__builtin_ctzll(rot) + (int)rr) & 63;
                float piv = useA ? __shfl(v0, lsel) : __shfl(v1, lsel);
                unsigned long long bgt0 = __ballot(v0 > piv) & a0;
                unsigned long long bgt1 = __ballot(v1 > piv) & a1;
                unsigned long long beq0 = __ballot(v0 == piv) & a0;
                unsigned long long beq1 = __ballot(v1 == piv) & a1;
                int cgt = (int)__popcll(bgt0) + (int)__popcll(bgt1);
                int ceq = (int)__popcll(beq0) + (int)__popcll(beq1);
                if (kp <= cgt) { a0 = bgt0; a1 = bgt1; }
                else if (kp <= cgt + ceq) { thr = piv; break; }
                else {
                    kp -= cgt + ceq;
                    a0 &= __ballot(v0 < piv);
                    a1 &= __ballot(v1 < piv);
                }
            }
        }

        float psum = 0.f, ox = 0.f, oy = 0.f;
#pragma unroll
        for (int j = 0; j < 18; ++j) {
            float p = (sc[j] >= thr) ? __expf(sc[j] - mx) : 0.f;
            psum += p;
            float2 vv = Vs[lane + 64*j];
            ox = fmaf(p, vv.x, ox);
            oy = fmaf(p, vv.y, oy);
        }
        for (int off = 32; off; off >>= 1) {
            psum += __shfl_xor(psum, off);
            ox   += __shfl_xor(ox, off);
            oy   += __shfl_xor(oy, off);
        }
        if (lane == 0) {
            float inv = 1.f / psum;
            float* op = o + ((size_t)(b*Sn + qrow))*6 + h*2;
            op[0] = ox*inv; op[1] = oy*inv;
        }
    }
}

// ---------------------------------------------------------------------------
// K4: o@Wo + residual + LN1 + FFN + residual + LN2 (+ optional next-layer QKV)
// ---------------------------------------------------------------------------
__global__ __launch_bounds__(128) void k_post(
    const float* __restrict__ xin, const float* __restrict__ ob,
    const float* __restrict__ Wo, const float* __restrict__ bo,
    const float* __restrict__ l1s, const float* __restrict__ l1b,
    const float* __restrict__ W1, const float* __restrict__ b1,
    const float* __restrict__ W2, const float* __restrict__ b2,
    const float* __restrict__ l2s, const float* __restrict__ l2b,
    float* __restrict__ xout,
    const float* __restrict__ Wq2, const float* __restrict__ Wk2,
    const float* __restrict__ Wv2, const float* __restrict__ bq2,
    const float* __restrict__ bk2, const float* __restrict__ bv2,
    float* __restrict__ q, float* __restrict__ k, float* __restrict__ v)
{
    int i = blockIdx.x * 128 + threadIdx.x;
    if (i >= Bn * Sn) return;
    float xr[6], orow[6];
#pragma unroll
    for (int e = 0; e < 6; ++e) {
        xr[e]   = xin[(size_t)i*6 + e];
        orow[e] = ob[(size_t)i*6 + e];
    }
    float rbuf[6];
#pragma unroll
    for (int j = 0; j < 6; ++j) {
        float a = bo[j];
#pragma unroll
        for (int e = 0; e < 6; ++e) a = fmaf(orow[e], Wo[e*6+j], a);
        rbuf[j] = xr[j] + a;
    }
    // LN1
    float mean = 0.f;
#pragma unroll
    for (int j = 0; j < 6; ++j) mean += rbuf[j];
    mean *= (1.f/6.f);
    float var = 0.f;
#pragma unroll
    for (int j = 0; j < 6; ++j) { float d = rbuf[j]-mean; var = fmaf(d, d, var); }
    var *= (1.f/6.f);
    float inv = rsqrtf(var + 1e-5f);
    float y1[6];
#pragma unroll
    for (int j = 0; j < 6; ++j) y1[j] = fmaf((rbuf[j]-mean)*inv, l1s[j], l1b[j]);
    // FFN
    float ff[12];
#pragma unroll
    for (int jj = 0; jj < 12; ++jj) {
        float a = b1[jj];
#pragma unroll
        for (int e = 0; e < 6; ++e) a = fmaf(y1[e], W1[e*12+jj], a);
        ff[jj] = fmaxf(a, 0.f);
    }
#pragma unroll
    for (int j = 0; j < 6; ++j) {
        float a = b2[j];
#pragma unroll
        for (int kk = 0; kk < 12; ++kk) a = fmaf(ff[kk], W2[kk*6+j], a);
        rbuf[j] = y1[j] + a;
    }
    // LN2
    mean = 0.f;
#pragma unroll
    for (int j = 0; j < 6; ++j) mean += rbuf[j];
    mean *= (1.f/6.f);
    var = 0.f;
#pragma unroll
    for (int j = 0; j < 6; ++j) { float d = rbuf[j]-mean; var = fmaf(d, d, var); }
    var *= (1.f/6.f);
    inv = rsqrtf(var + 1e-5f);
    float xo[6];
#pragma unroll
    for (int j = 0; j < 6; ++j) {
        xo[j] = fmaf((rbuf[j]-mean)*inv, l2s[j], l2b[j]);
        xout[(size_t)i*6 + j] = xo[j];
    }
    if (Wq2) {  // fused next-layer QKV (wave-uniform branch)
#pragma unroll
        for (int j = 0; j < 6; ++j) {
            float aq = bq2[j], ak = bk2[j], av = bv2[j];
#pragma unroll
            for (int e = 0; e < 6; ++e) {
                aq = fmaf(xo[e], Wq2[e*6+j], aq);
                ak = fmaf(xo[e], Wk2[e*6+j], ak);
                av = fmaf(xo[e], Wv2[e*6+j], av);
            }
            q[(size_t)i*6+j] = aq; k[(size_t)i*6+j] = ak; v[(size_t)i*6+j] = av;
        }
    }
}

// ---------------------------------------------------------------------------
// K5: GI = Y[0:8] @ Wih^T + bih   (Y rows are contiguous slices of x)
// ---------------------------------------------------------------------------
__global__ __launch_bounds__(256) void k_gi(
    const float* __restrict__ x, const float* __restrict__ Wih,
    const float* __restrict__ bih, float* __restrict__ GI)
{
    int bx = blockIdx.x;               // 8 * 144 blocks
    int w  = bx / 144, jb = bx % 144;
    int wave = threadIdx.x >> 6, lane = threadIdx.x & 63;
    int bq = lane >> 4, kg = lane & 15;
    int j0 = jb*16 + wave*4;

    float acc[4][4];                   // [jl][bb]
#pragma unroll
    for (int a = 0; a < 4; ++a)
#pragma unroll
        for (int c = 0; c < 4; ++c) acc[a][c] = 0.f;

#pragma unroll
    for (int c = 0; c < 3; ++c) {      // k chunks of 16 (total 48 per lane)
        float4 wv[4][4];
#pragma unroll
        for (int jl = 0; jl < 4; ++jl) {
            const float4* wp = (const float4*)(Wih + (size_t)(j0+jl)*768 + kg*48 + c*16);
#pragma unroll
            for (int t = 0; t < 4; ++t) wv[jl][t] = wp[t];
        }
#pragma unroll
        for (int bb = 0; bb < 4; ++bb) {
            int b = bq*4 + bb;
            const float4* hp = (const float4*)(x + (size_t)(b*Sn + w*Fn)*6 + kg*48 + c*16);
#pragma unroll
            for (int t = 0; t < 4; ++t) {
                float4 hv = hp[t];
#pragma unroll
                for (int jl = 0; jl < 4; ++jl) {
                    acc[jl][bb] = fmaf(hv.x, wv[jl][t].x, acc[jl][bb]);
                    acc[jl][bb] = fmaf(hv.y, wv[jl][t].y, acc[jl][bb]);
                    acc[jl][bb] = fmaf(hv.z, wv[jl][t].z, acc[jl][bb]);
                    acc[jl][bb] = fmaf(hv.w, wv[jl][t].w, acc[jl][bb]);
                }
            }
        }
    }
#pragma unroll
    for (int m = 1; m <= 8; m <<= 1)
#pragma unroll
        for (int jl = 0; jl < 4; ++jl)
#pragma unroll
            for (int bb = 0; bb < 4; ++bb)
                acc[jl][bb] += __shfl_xor(acc[jl][bb], m);
    if (kg == 0) {
#pragma unroll
        for (int jl = 0; jl < 4; ++jl) {
            float bi = bih[j0+jl];
#pragma unroll
            for (int bb = 0; bb < 4; ++bb) {
                int b = bq*4 + bb;
                GI[((size_t)(w*16 + b))*2304 + j0 + jl] = acc[jl][bb] + bi;
            }
        }
    }
}

// ---------------------------------------------------------------------------
// K6: one GRU step: gh = h@Whh^T (+bhh), gates, h_new. block=3 waves (r,z,n),
// each wave 2 n-columns x 16 batch; gate fusion via tiny LDS exchange
// ---------------------------------------------------------------------------
__global__ __launch_bounds__(192) void k_gru(
    const float* __restrict__ hprev, const float* __restrict__ GIw,
    const float* __restrict__ Whh, const float* __restrict__ bhh,
    float* __restrict__ hnew)
{
    __shared__ float ghs[3][2][16];
    int g = threadIdx.x >> 6, lane = threadIdx.x & 63;
    int bq = lane >> 4, kg = lane & 15;
    int n0 = blockIdx.x * 2;

    float acc[2][4];
#pragma unroll
    for (int a = 0; a < 2; ++a)
#pragma unroll
        for (int c = 0; c < 4; ++c) acc[a][c] = 0.f;

#pragma unroll
    for (int c = 0; c < 3; ++c) {
        float4 w0[4], w1[4];
        const float4* wp0 = (const float4*)(Whh + (size_t)(g*768 + n0)*768 + kg*48 + c*16);
        const float4* wp1 = (const float4*)(Whh + (size_t)(g*768 + n0 + 1)*768 + kg*48 + c*16);
#pragma unroll
        for (int t = 0; t < 4; ++t) { w0[t] = wp0[t]; w1[t] = wp1[t]; }
#pragma unroll
        for (int bb = 0; bb < 4; ++bb) {
            int b = bq*4 + bb;
            const float4* hp = (const float4*)(hprev + (size_t)b*768 + kg*48 + c*16);
#pragma unroll
            for (int t = 0; t < 4; ++t) {
                float4 hv = hp[t];
                acc[0][bb] = fmaf(hv.x, w0[t].x, acc[0][bb]);
                acc[0][bb] = fmaf(hv.y, w0[t].y, acc[0][bb]);
                acc[0][bb] = fmaf(hv.z, w0[t].z, acc[0][bb]);
                acc[0][bb] = fmaf(hv.w, w0[t].w, acc[0][bb]);
                acc[1][bb] = fmaf(hv.x, w1[t].x, acc[1][bb]);
                acc[1][bb] = fmaf(hv.y, w1[t].y, acc[1][bb]);
                acc[1][bb] = fmaf(hv.z, w1[t].z, acc[1][bb]);
                acc[1][bb] = fmaf(hv.w, w1[t].w, acc[1][bb]);
            }
        }
    }
#pragma unroll
    for (int m = 1; m <= 8; m <<= 1)
#pragma unroll
        for (int jl = 0; jl < 2; ++jl)
#pragma unroll
            for (int bb = 0; bb < 4; ++bb)
                acc[jl][bb] += __shfl_xor(acc[jl][bb], m);
    if (kg == 0) {
#pragma unroll
        for (int jl = 0; jl < 2; ++jl)
#pragma unroll
            for (int bb = 0; bb < 4; ++bb)
                ghs[g][jl][bq*4+bb] = acc[jl][bb];
    }
    __syncthreads();
    if (threadIdx.x < 32) {
        int b = threadIdx.x & 15, jl = threadIdx.x >> 4;
        int n = n0 + jl;
        float ghr = ghs[0][jl][b] + bhh[n];
        float ghz = ghs[1][jl][b] + bhh[768+n];
        float ghn = ghs[2][jl][b] + bhh[1536+n];
        const float* gib = GIw + (size_t)b*2304;
        float rr = sigmoidf_(gib[n] + ghr);
        float zz = sigmoidf_(gib[768+n] + ghz);
        float nn = tanhf(gib[1536+n] + rr*ghn);
        hnew[(size_t)b*768 + n] = fmaf(-zz, nn, nn) + zz*hprev[(size_t)b*768 + n];
    }
}

// ---------------------------------------------------------------------------
// K7: out = sigmoid(h @ fcn_W + fcn_b)
// ---------------------------------------------------------------------------
__global__ __launch_bounds__(128) void k_final(
    const float* __restrict__ h, const float* __restrict__ fW,
    const float* __restrict__ fb, float* __restrict__ out)
{
    __shared__ float hs[768];
    int b = blockIdx.x, f = threadIdx.x;
    for (int i = threadIdx.x; i < 768; i += 128) hs[i] = h[(size_t)b*768 + i];
    __syncthreads();
    float a0 = fb[f], a1 = 0.f, a2 = 0.f, a3 = 0.f;
#pragma unroll 4
    for (int k = 0; k < 768; k += 4) {
        a0 = fmaf(hs[k+0], fW[(size_t)(k+0)*128 + f], a0);
        a1 = fmaf(hs[k+1], fW[(size_t)(k+1)*128 + f], a1);
        a2 = fmaf(hs[k+2], fW[(size_t)(k+2)*128 + f], a2);
        a3 = fmaf(hs[k+3], fW[(size_t)(k+3)*128 + f], a3);
    }
    out[(size_t)b*128 + f] = sigmoidf_((a0+a1)+(a2+a3));
}

// ---------------------------------------------------------------------------
extern "C" void kernel_launch(void* const* d_in, const int* in_sizes, int n_in,
                              void* d_out, int out_size, void* d_ws, size_t ws_size,
                              hipStream_t stream)
{
    const float* src   = (const float*)d_in[0];
    const float* w1w   = (const float*)d_in[1];
    const float* w1b   = (const float*)d_in[2];
    const float* w2w   = (const float*)d_in[3];
    const float* w2b   = (const float*)d_in[4];
    const float* meta  = (const float*)d_in[5];
    const float* pos   = (const float*)d_in[6];
    const float* Wq    = (const float*)d_in[7];
    const float* Wk    = (const float*)d_in[8];
    const float* Wv    = (const float*)d_in[9];
    const float* Wo    = (const float*)d_in[10];
    const float* bq    = (const float*)d_in[11];
    const float* bk    = (const float*)d_in[12];
    const float* bv    = (const float*)d_in[13];
    const float* bo    = (const float*)d_in[14];
    const float* l1s   = (const float*)d_in[15];
    const float* l1b   = (const float*)d_in[16];
    const float* W1    = (const float*)d_in[17];
    const float* b1    = (const float*)d_in[18];
    const float* W2    = (const float*)d_in[19];
    const float* b2    = (const float*)d_in[20];
    const float* l2s   = (const float*)d_in[21];
    const float* l2b   = (const float*)d_in[22];
    const float* Wih   = (const float*)d_in[23];
    const float* Whh   = (const float*)d_in[24];
    const float* bih   = (const float*)d_in[25];
    const float* bhh   = (const float*)d_in[26];
    const float* hini  = (const float*)d_in[27];
    const float* fW    = (const float*)d_in[28];
    const float* fb    = (const float*)d_in[29];

    float* ws = (float*)d_ws;
    float* x  = ws;                 // 110592
    float* q  = x  + 110592;
    float* k  = q  + 110592;
    float* v  = k  + 110592;
    float* o  = v  + 110592;
    float* GI = o  + 110592;        // 294912
    float* h0 = GI + 294912;        // 12288
    float* h1 = h0 + 12288;

    k_autodis_qkv<<<144, 128, 0, stream>>>(src, w1w, w1b, w2w, w2b, meta, pos,
                                           Wq, Wk, Wv, bq, bk, bv, x, q, k, v);

    for (int l = 0; l < NLn; ++l) {
        k_attn<<<Bn*NHn*72, 1024, 0, stream>>>(q, k, v, o);
        bool nx = (l + 1 < NLn);
        k_post<<<144, 128, 0, stream>>>(x, o, Wo + l*36, bo + l*6,
                                        l1s + l*6, l1b + l*6,
                                        W1 + l*72, b1 + l*12,
                                        W2 + l*72, b2 + l*6,
                                        l2s + l*6, l2b + l*6, x,
                                        nx ? Wq + (l+1)*36 : nullptr,
                                        nx ? Wk + (l+1)*36 : nullptr,
                                        nx ? Wv + (l+1)*36 : nullptr,
                                        nx ? bq + (l+1)*6  : nullptr,
                                        nx ? bk + (l+1)*6  : nullptr,
                                        nx ? bv + (l+1)*6  : nullptr,
                                        q, k, v);
    }

    k_gi<<<8*144, 256, 0, stream>>>(x, Wih, bih, GI);

    const float* hcur = hini;
    float* hb[2] = {h0, h1};
    for (int w = 0; w < 8; ++w) {
        float* hn = hb[w & 1];
        k_gru<<<384, 192, 0, stream>>>(hcur, GI + (size_t)w*16*2304, Whh, bhh, hn);
        hcur = hn;
    }

    k_final<<<16, 128, 0, stream>>>(hcur, fW, fb, (float*)d_out);
}

// Round 16
// 436.328 us; speedup vs baseline: 1.0368x; 1.0104x over previous
//
#include <hip/hip_runtime.h>
#include <hip/hip_bf16.h>
#include <math.h>

// Problem constants
#define Fn   128
#define Wn   9
#define Bn   16
#define En   6
#define NHn  3
#define NLn  3
#define FFDn 12
#define HIDn 768       // F*E
#define Sn   1152      // W*F
#define TOPMn 99
#define DHn  2

__device__ __forceinline__ float sigmoidf_(float x) {
    return 1.0f / (1.0f + __expf(-x));
}

// order-preserving float<->uint key mapping (total order)
__device__ __forceinline__ unsigned f2k(float f) {
    unsigned b = __float_as_uint(f);
    return (b & 0x80000000u) ? ~b : (b | 0x80000000u);
}
__device__ __forceinline__ float k2f(unsigned k) {
    return __uint_as_float((k & 0x80000000u) ? (k & 0x7FFFFFFFu) : ~k);
}

// ---------------------------------------------------------------------------
// K1: AutoDis + positional embedding -> x [B,S,E], fused layer-0 QKV
// ---------------------------------------------------------------------------
__global__ __launch_bounds__(128) void k_autodis_qkv(
    const float* __restrict__ src, const float* __restrict__ w1w,
    const float* __restrict__ w1b, const float* __restrict__ w2w,
    const float* __restrict__ w2b, const float* __restrict__ meta,
    const float* __restrict__ pos, const float* __restrict__ Wq,
    const float* __restrict__ Wk, const float* __restrict__ Wv,
    const float* __restrict__ bq, const float* __restrict__ bk,
    const float* __restrict__ bv,
    float* __restrict__ x, float* __restrict__ q,
    float* __restrict__ k, float* __restrict__ v)
{
    int i = blockIdx.x * 128 + threadIdx.x;   // over W*B*F = 18432
    if (i >= Wn * Bn * Fn) return;
    int f = i & 127;
    int b = (i >> 7) & 15;
    int w = i >> 11;

    float s = src[i];
    float h1[6];
#pragma unroll
    for (int j = 0; j < 6; ++j) {
        float t = fmaf(s, w1w[f*6+j], w1b[f*6+j]);
        h1[j] = t >= 0.f ? t : 0.01f * t;          // LeakyReLU 0.01
    }
    float tt[6];
    float mx = -3.0e38f;
#pragma unroll
    for (int j = 0; j < 6; ++j) {
        float a = w2b[f*6+j];
#pragma unroll
        for (int kk = 0; kk < 6; ++kk) a = fmaf(h1[kk], w2w[(f*6+kk)*6+j], a);
        a = fmaf(0.5f, h1[j], a);                  // + CTRL*h1
        tt[j] = a;
        mx = fmaxf(mx, a);
    }
    float e[6], sum = 0.f;
#pragma unroll
    for (int j = 0; j < 6; ++j) { e[j] = __expf((tt[j]-mx) * 1e5f); sum += e[j]; }
    float isum = 1.f / sum;
    int srow = w*Fn + f;
    size_t row = (size_t)(b*Sn + srow);
    float xr[6];
#pragma unroll
    for (int ee = 0; ee < 6; ++ee) {
        float a = 0.f;
#pragma unroll
        for (int kk = 0; kk < 6; ++kk) a = fmaf(e[kk], meta[(f*6+kk)*6+ee], a);
        xr[ee] = fmaf(a * isum, 2.449489742783178f, pos[srow*6+ee]);
        x[row*6 + ee] = xr[ee];
    }
    // layer-0 QKV
#pragma unroll
    for (int j = 0; j < 6; ++j) {
        float aq = bq[j], ak = bk[j], av = bv[j];
#pragma unroll
        for (int ee = 0; ee < 6; ++ee) {
            aq = fmaf(xr[ee], Wq[ee*6+j], aq);
            ak = fmaf(xr[ee], Wk[ee*6+j], ak);
            av = fmaf(xr[ee], Wv[ee*6+j], av);
        }
        q[row*6+j] = aq; k[row*6+j] = ak; v[row*6+j] = av;
    }
}

// ---------------------------------------------------------------------------
// K3: fused attention (R14-verified geometry: 72 chunks of 16 rows, 4 waves
// x 4 sequential rows, K and V staged in LDS). Exact top-99 threshold:
//  A: 2 seed probes (cnt==99 -> exact set, done)
//  B: data-pivot probes while cl-ch>128 (cnt==99 exit; key-midpoint /4th)
//  C: compact candidates to LDS; ballot quickselect with a FAST PATH:
//     ncand<=64 (the common case after good seeds) uses the single-register
//     loop (half the ballots/masks per round); ncand in 65..128 uses the
//     2-register loop. Pivot always a live value -> |active| strictly
//     decreases -> terminates on == branch with thr == s_99.
// Exactness: cl=cnt(>=flo)>=99>ch=cnt(>=fhi) with exact ballot counts;
// selected SET always equals jax's {s >= top_k[..,-1]} incl. ties.
// ---------------------------------------------------------------------------
__global__ __launch_bounds__(256) void k_attn(
    const float* __restrict__ q, const float* __restrict__ kbuf,
    const float* __restrict__ vbuf, float* __restrict__ o)
{
    __shared__ float2 Ks[Sn];
    __shared__ float2 Vs[Sn];
    __shared__ float cbuf[4][128];
    int bx = blockIdx.x;
    int qc = bx % 72;              // 72 q-chunks of 16 rows
    int bh = bx / 72;
    int h = bh % NHn, b = bh / NHn;
    int lane = threadIdx.x & 63, wave = threadIdx.x >> 6;

    for (int idx = threadIdx.x; idx < Sn; idx += 256) {
        Ks[idx] = *(const float2*)(kbuf + ((size_t)(b*Sn + idx))*6 + h*2);
        Vs[idx] = *(const float2*)(vbuf + ((size_t)(b*Sn + idx))*6 + h*2);
    }
    __syncthreads();

    const float scale = 0.70710678118654752f;  // 1/sqrt(DH)
#pragma unroll 1
    for (int r = 0; r < 4; ++r) {
        int qrow = qc*16 + wave*4 + r;
        const float* qp = q + ((size_t)(b*Sn + qrow))*6 + h*2;
        float qx = qp[0]*scale, qy = qp[1]*scale;

        float sc[18];
        float mx = -3.0e38f, s1 = 0.f, s2 = 0.f;
#pragma unroll
        for (int j = 0; j < 18; ++j) {
            float2 kk = Ks[lane + 64*j];
            float s = fmaf(qx, kk.x, qy*kk.y);
            sc[j] = s;
            mx = fmaxf(mx, s);
            s1 += s; s2 = fmaf(s, s, s2);
        }
        for (int off = 32; off; off >>= 1) {
            mx = fmaxf(mx, __shfl_xor(mx, off));
            s1 += __shfl_xor(s1, off);
            s2 += __shfl_xor(s2, off);
        }
        mx = __uint_as_float(__builtin_amdgcn_readfirstlane(__float_as_uint(mx)));
        s1 = __uint_as_float(__builtin_amdgcn_readfirstlane(__float_as_uint(s1)));
        s2 = __uint_as_float(__builtin_amdgcn_readfirstlane(__float_as_uint(s2)));

        const float invN = 1.0f/1152.0f;
        float mu = s1*invN;
        float sg = sqrtf(fmaxf(fmaf(-mu, mu, s2*invN), 0.f) + 1e-20f);

        float flo = -3.0e38f;                  // cnt(>=flo) = 1152
        float fhi = k2f(f2k(mx) + 1u);         // cnt(>=fhi) = 0
        int cl = 1152, ch = 0;
        float thr = flo;
        bool resolved = false;
        float lastf = 0.f; int lastc = 0;

        // ---- Phase A: 2 seed probes (cnt==99 -> done) ----
#pragma unroll 1
        for (int s = 0; s < 2; ++s) {
            unsigned klo = f2k(flo), khi = f2k(fhi);
            if (khi - klo <= 1u) break;
            float t = (s == 0) ? fmaf(1.366f, sg, mu)
                               : fmaf((float)(lastc - 99)*0.005543f, sg, lastf);
            unsigned tk = f2k(t);
            if (tk <= klo) tk = klo + 1u; else if (tk >= khi) tk = khi - 1u;
            t = k2f(tk);
            int cnt = 0;
#pragma unroll
            for (int j = 0; j < 18; ++j)
                cnt += (int)__popcll(__ballot(sc[j] >= t));
            if (cnt == 99) { thr = t; resolved = true; break; }  // exact set
            if (cnt > 99) { flo = t; cl = cnt; } else { fhi = t; ch = cnt; }
            lastf = t; lastc = cnt;
        }

        // ---- Phase B: data-pivot probes (key-midpoint every 4th) ----
        if (!resolved) {
#pragma unroll 1
            for (int it = 0; it < 200 && (cl - ch) > 128; ++it) {
                float cval = 0.f; bool have = false;
#pragma unroll
                for (int j = 0; j < 18; ++j) {
                    bool c = (sc[j] > flo) && (sc[j] < fhi);
                    cval = c ? sc[j] : cval;
                    have = have || c;
                }
                unsigned long long m = __ballot(have);
                if (m == 0ull) { thr = flo; resolved = true; break; }
                float t;
                if ((it & 3) == 3) {               // key-space midpoint safety
                    unsigned klo = f2k(flo), khi = f2k(fhi);
                    unsigned tk = klo + ((khi - klo) >> 1);
                    if (tk <= klo) tk = klo + 1u;
                    if (tk >= khi) tk = khi - 1u;
                    t = k2f(tk);
                } else {                           // data pivot (rotating lane)
                    unsigned rr = (unsigned)(it * 23) & 63u;
                    unsigned long long rot =
                        rr ? ((m >> rr) | (m << (64u - rr))) : m;
                    int lsel = (__builtin_ctzll(rot) + (int)rr) & 63;
                    t = __shfl(cval, lsel);
                }
                int cnt = 0;
#pragma unroll
                for (int j = 0; j < 18; ++j)
                    cnt += (int)__popcll(__ballot(sc[j] >= t));
                if (cnt == 99) { thr = t; resolved = true; break; }  // exact set
                if (cnt > 99) { flo = t; cl = cnt; } else { fhi = t; ch = cnt; }
            }
        }

        if (!resolved) {
            // ---- Phase C: compact candidates [flo,fhi) -> LDS ----
            int ncand = cl - ch;               // 1..128 guaranteed here
            int myn = 0;
#pragma unroll
            for (int j = 0; j < 18; ++j)
                myn += ((sc[j] >= flo) && (sc[j] < fhi)) ? 1 : 0;
            int pre = myn;
#pragma unroll
            for (int d = 1; d < 64; d <<= 1) {
                int t2 = __shfl_up(pre, d);
                if (lane >= d) pre += t2;
            }
            pre -= myn;                        // exclusive prefix
            int idx = pre;
#pragma unroll
            for (int j = 0; j < 18; ++j) {
                if ((sc[j] >= flo) && (sc[j] < fhi)) {
                    if (idx < 128) cbuf[wave][idx] = sc[j];
                    ++idx;
                }
            }
            __builtin_amdgcn_wave_barrier();
            int kp = 99 - ch;                  // 1..ncand
            if (ncand <= 64) {
                // fast path: 1 value/lane quickselect
                float val = (lane < ncand) ? cbuf[wave][lane] : 0.f;
                unsigned long long active = __ballot(lane < ncand);
#pragma unroll 1
                for (int it = 0; it < 200; ++it) {
                    unsigned rr = (unsigned)(it * 23) & 63u;
                    unsigned long long rot =
                        rr ? ((active >> rr) | (active << (64u - rr))) : active;
                    int lsel = (__builtin_ctzll(rot) + (int)rr) & 63;
                    float piv = __shfl(val, lsel);
                    unsigned long long bgt = __ballot(val > piv) & active;
                    unsigned long long beq = __ballot(val == piv) & active;
                    int cgt = (int)__popcll(bgt), ceq = (int)__popcll(beq);
                    if (kp <= cgt) { active = bgt; }
                    else if (kp <= cgt + ceq) { thr = piv; break; }
                    else { kp -= cgt + ceq; active &= __ballot(val < piv); }
                }
            } else {
                // 2 values/lane quickselect (65..128 candidates)
                float v0 = cbuf[wave][lane];
                float v1 = (lane + 64 < ncand) ? cbuf[wave][lane + 64] : 0.f;
                unsigned long long a0 = ~0ull;
                unsigned long long a1 = __ballot(lane + 64 < ncand);
#pragma unroll 1
                for (int it = 0; it < 200; ++it) {
                    bool useA = (a0 != 0ull);
                    unsigned long long m = useA ? a0 : a1;
                    unsigned rr = (unsigned)(it * 23) & 63u;
                    unsigned long long rot =
                        rr ? ((m >> rr) | (m << (64u - rr))) : m;
                    int lsel = (__builtin_ctzll(rot) + (int)rr) & 63;
                    float piv = useA ? __shfl(v0, lsel) : __shfl(v1, lsel);
                    unsigned long long bgt0 = __ballot(v0 > piv) & a0;
                    unsigned long long bgt1 = __ballot(v1 > piv) & a1;
                    unsigned long long beq0 = __ballot(v0 == piv) & a0;
                    unsigned long long beq1 = __ballot(v1 == piv) & a1;
                    int cgt = (int)__popcll(bgt0) + (int)__popcll(bgt1);
                    int ceq = (int)__popcll(beq0) + (int)__popcll(beq1);
                    if (kp <= cgt) { a0 = bgt0; a1 = bgt1; }
                    else if (kp <= cgt + ceq) { thr = piv; break; }
                    else {
                        kp -= cgt + ceq;
                        a0 &= __ballot(v0 < piv);
                        a1 &= __ballot(v1 < piv);
                    }
                }
            }
        }

        float psum = 0.f, ox = 0.f, oy = 0.f;
#pragma unroll
        for (int j = 0; j < 18; ++j) {
            float p = (sc[j] >= thr) ? __expf(sc[j] - mx) : 0.f;
            psum += p;
            float2 vv = Vs[lane + 64*j];
            ox = fmaf(p, vv.x, ox);
            oy = fmaf(p, vv.y, oy);
        }
        for (int off = 32; off; off >>= 1) {
            psum += __shfl_xor(psum, off);
            ox   += __shfl_xor(ox, off);
            oy   += __shfl_xor(oy, off);
        }
        if (lane == 0) {
            float inv = 1.f / psum;
            float* op = o + ((size_t)(b*Sn + qrow))*6 + h*2;
            op[0] = ox*inv; op[1] = oy*inv;
        }
    }
}

// ---------------------------------------------------------------------------
// K4: o@Wo + residual + LN1 + FFN + residual + LN2 (+ optional next-layer QKV)
// ---------------------------------------------------------------------------
__global__ __launch_bounds__(128) void k_post(
    const float* __restrict__ xin, const float* __restrict__ ob,
    const float* __restrict__ Wo, const float* __restrict__ bo,
    const float* __restrict__ l1s, const float* __restrict__ l1b,
    const float* __restrict__ W1, const float* __restrict__ b1,
    const float* __restrict__ W2, const float* __restrict__ b2,
    const float* __restrict__ l2s, const float* __restrict__ l2b,
    float* __restrict__ xout,
    const float* __restrict__ Wq2, const float* __restrict__ Wk2,
    const float* __restrict__ Wv2, const float* __restrict__ bq2,
    const float* __restrict__ bk2, const float* __restrict__ bv2,
    float* __restrict__ q, float* __restrict__ k, float* __restrict__ v)
{
    int i = blockIdx.x * 128 + threadIdx.x;
    if (i >= Bn * Sn) return;
    float xr[6], orow[6];
#pragma unroll
    for (int e = 0; e < 6; ++e) {
        xr[e]   = xin[(size_t)i*6 + e];
        orow[e] = ob[(size_t)i*6 + e];
    }
    float rbuf[6];
#pragma unroll
    for (int j = 0; j < 6; ++j) {
        float a = bo[j];
#pragma unroll
        for (int e = 0; e < 6; ++e) a = fmaf(orow[e], Wo[e*6+j], a);
        rbuf[j] = xr[j] + a;
    }
    // LN1
    float mean = 0.f;
#pragma unroll
    for (int j = 0; j < 6; ++j) mean += rbuf[j];
    mean *= (1.f/6.f);
    float var = 0.f;
#pragma unroll
    for (int j = 0; j < 6; ++j) { float d = rbuf[j]-mean; var = fmaf(d, d, var); }
    var *= (1.f/6.f);
    float inv = rsqrtf(var + 1e-5f);
    float y1[6];
#pragma unroll
    for (int j = 0; j < 6; ++j) y1[j] = fmaf((rbuf[j]-mean)*inv, l1s[j], l1b[j]);
    // FFN
    float ff[12];
#pragma unroll
    for (int jj = 0; jj < 12; ++jj) {
        float a = b1[jj];
#pragma unroll
        for (int e = 0; e < 6; ++e) a = fmaf(y1[e], W1[e*12+jj], a);
        ff[jj] = fmaxf(a, 0.f);
    }
#pragma unroll
    for (int j = 0; j < 6; ++j) {
        float a = b2[j];
#pragma unroll
        for (int kk = 0; kk < 12; ++kk) a = fmaf(ff[kk], W2[kk*6+j], a);
        rbuf[j] = y1[j] + a;
    }
    // LN2
    mean = 0.f;
#pragma unroll
    for (int j = 0; j < 6; ++j) mean += rbuf[j];
    mean *= (1.f/6.f);
    var = 0.f;
#pragma unroll
    for (int j = 0; j < 6; ++j) { float d = rbuf[j]-mean; var = fmaf(d, d, var); }
    var *= (1.f/6.f);
    inv = rsqrtf(var + 1e-5f);
    float xo[6];
#pragma unroll
    for (int j = 0; j < 6; ++j) {
        xo[j] = fmaf((rbuf[j]-mean)*inv, l2s[j], l2b[j]);
        xout[(size_t)i*6 + j] = xo[j];
    }
    if (Wq2) {  // fused next-layer QKV (wave-uniform branch)
#pragma unroll
        for (int j = 0; j < 6; ++j) {
            float aq = bq2[j], ak = bk2[j], av = bv2[j];
#pragma unroll
            for (int e = 0; e < 6; ++e) {
                aq = fmaf(xo[e], Wq2[e*6+j], aq);
                ak = fmaf(xo[e], Wk2[e*6+j], ak);
                av = fmaf(xo[e], Wv2[e*6+j], av);
            }
            q[(size_t)i*6+j] = aq; k[(size_t)i*6+j] = ak; v[(size_t)i*6+j] = av;
        }
    }
}

// ---------------------------------------------------------------------------
// K5: GI = Y[0:8] @ Wih^T + bih   (Y rows are contiguous slices of x)
// ---------------------------------------------------------------------------
__global__ __launch_bounds__(256) void k_gi(
    const float* __restrict__ x, const float* __restrict__ Wih,
    const float* __restrict__ bih, float* __restrict__ GI)
{
    int bx = blockIdx.x;               // 8 * 144 blocks
    int w  = bx / 144, jb = bx % 144;
    int wave = threadIdx.x >> 6, lane = threadIdx.x & 63;
    int bq = lane >> 4, kg = lane & 15;
    int j0 = jb*16 + wave*4;

    float acc[4][4];                   // [jl][bb]
#pragma unroll
    for (int a = 0; a < 4; ++a)
#pragma unroll
        for (int c = 0; c < 4; ++c) acc[a][c] = 0.f;

#pragma unroll
    for (int c = 0; c < 3; ++c) {      // k chunks of 16 (total 48 per lane)
        float4 wv[4][4];
#pragma unroll
        for (int jl = 0; jl < 4; ++jl) {
            const float4* wp = (const float4*)(Wih + (size_t)(j0+jl)*768 + kg*48 + c*16);
#pragma unroll
            for (int t = 0; t < 4; ++t) wv[jl][t] = wp[t];
        }
#pragma unroll
        for (int bb = 0; bb < 4; ++bb) {
            int b = bq*4 + bb;
            const float4* hp = (const float4*)(x + (size_t)(b*Sn + w*Fn)*6 + kg*48 + c*16);
#pragma unroll
            for (int t = 0; t < 4; ++t) {
                float4 hv = hp[t];
#pragma unroll
                for (int jl = 0; jl < 4; ++jl) {
                    acc[jl][bb] = fmaf(hv.x, wv[jl][t].x, acc[jl][bb]);
                    acc[jl][bb] = fmaf(hv.y, wv[jl][t].y, acc[jl][bb]);
                    acc[jl][bb] = fmaf(hv.z, wv[jl][t].z, acc[jl][bb]);
                    acc[jl][bb] = fmaf(hv.w, wv[jl][t].w, acc[jl][bb]);
                }
            }
        }
    }
#pragma unroll
    for (int m = 1; m <= 8; m <<= 1)
#pragma unroll
        for (int jl = 0; jl < 4; ++jl)
#pragma unroll
            for (int bb = 0; bb < 4; ++bb)
                acc[jl][bb] += __shfl_xor(acc[jl][bb], m);
    if (kg == 0) {
#pragma unroll
        for (int jl = 0; jl < 4; ++jl) {
            float bi = bih[j0+jl];
#pragma unroll
            for (int bb = 0; bb < 4; ++bb) {
                int b = bq*4 + bb;
                GI[((size_t)(w*16 + b))*2304 + j0 + jl] = acc[jl][bb] + bi;
            }
        }
    }
}

// ---------------------------------------------------------------------------
// K6: one GRU step: gh = h@Whh^T (+bhh), gates, h_new. block=3 waves (r,z,n),
// each wave 2 n-columns x 16 batch; gate fusion via tiny LDS exchange
// ---------------------------------------------------------------------------
__global__ __launch_bounds__(192) void k_gru(
    const float* __restrict__ hprev, const float* __restrict__ GIw,
    const float* __restrict__ Whh, const float* __restrict__ bhh,
    float* __restrict__ hnew)
{
    __shared__ float ghs[3][2][16];
    int g = threadIdx.x >> 6, lane = threadIdx.x & 63;
    int bq = lane >> 4, kg = lane & 15;
    int n0 = blockIdx.x * 2;

    float acc[2][4];
#pragma unroll
    for (int a = 0; a < 2; ++a)
#pragma unroll
        for (int c = 0; c < 4; ++c) acc[a][c] = 0.f;

#pragma unroll
    for (int c = 0; c < 3; ++c) {
        float4 w0[4], w1[4];
        const float4* wp0 = (const float4*)(Whh + (size_t)(g*768 + n0)*768 + kg*48 + c*16);
        const float4* wp1 = (const float4*)(Whh + (size_t)(g*768 + n0 + 1)*768 + kg*48 + c*16);
#pragma unroll
        for (int t = 0; t < 4; ++t) { w0[t] = wp0[t]; w1[t] = wp1[t]; }
#pragma unroll
        for (int bb = 0; bb < 4; ++bb) {
            int b = bq*4 + bb;
            const float4* hp = (const float4*)(hprev + (size_t)b*768 + kg*48 + c*16);
#pragma unroll
            for (int t = 0; t < 4; ++t) {
                float4 hv = hp[t];
                acc[0][bb] = fmaf(hv.x, w0[t].x, acc[0][bb]);
                acc[0][bb] = fmaf(hv.y, w0[t].y, acc[0][bb]);
                acc[0][bb] = fmaf(hv.z, w0[t].z, acc[0][bb]);
                acc[0][bb] = fmaf(hv.w, w0[t].w, acc[0][bb]);
                acc[1][bb] = fmaf(hv.x, w1[t].x, acc[1][bb]);
                acc[1][bb] = fmaf(hv.y, w1[t].y, acc[1][bb]);
                acc[1][bb] = fmaf(hv.z, w1[t].z, acc[1][bb]);
                acc[1][bb] = fmaf(hv.w, w1[t].w, acc[1][bb]);
            }
        }
    }
#pragma unroll
    for (int m = 1; m <= 8; m <<= 1)
#pragma unroll
        for (int jl = 0; jl < 2; ++jl)
#pragma unroll
            for (int bb = 0; bb < 4; ++bb)
                acc[jl][bb] += __shfl_xor(acc[jl][bb], m);
    if (kg == 0) {
#pragma unroll
        for (int jl = 0; jl < 2; ++jl)
#pragma unroll
            for (int bb = 0; bb < 4; ++bb)
                ghs[g][jl][bq*4+bb] = acc[jl][bb];
    }
    __syncthreads();
    if (threadIdx.x < 32) {
        int b = threadIdx.x & 15, jl = threadIdx.x >> 4;
        int n = n0 + jl;
        float ghr = ghs[0][jl][b] + bhh[n];
        float ghz = ghs[1][jl][b] + bhh[768+n];
        float ghn = ghs[2][jl][b] + bhh[1536+n];
        const float* gib = GIw + (size_t)b*2304;
        float rr = sigmoidf_(gib[n] + ghr);
        float zz = sigmoidf_(gib[768+n] + ghz);
        float nn = tanhf(gib[1536+n] + rr*ghn);
        hnew[(size_t)b*768 + n] = fmaf(-zz, nn, nn) + zz*hprev[(size_t)b*768 + n];
    }
}

// ---------------------------------------------------------------------------
// K7: out = sigmoid(h @ fcn_W + fcn_b)
// ---------------------------------------------------------------------------
__global__ __launch_bounds__(128) void k_final(
    const float* __restrict__ h, const float* __restrict__ fW,
    const float* __restrict__ fb, float* __restrict__ out)
{
    __shared__ float hs[768];
    int b = blockIdx.x, f = threadIdx.x;
    for (int i = threadIdx.x; i < 768; i += 128) hs[i] = h[(size_t)b*768 + i];
    __syncthreads();
    float a0 = fb[f], a1 = 0.f, a2 = 0.f, a3 = 0.f;
#pragma unroll 4
    for (int k = 0; k < 768; k += 4) {
        a0 = fmaf(hs[k+0], fW[(size_t)(k+0)*128 + f], a0);
        a1 = fmaf(hs[k+1], fW[(size_t)(k+1)*128 + f], a1);
        a2 = fmaf(hs[k+2], fW[(size_t)(k+2)*128 + f], a2);
        a3 = fmaf(hs[k+3], fW[(size_t)(k+3)*128 + f], a3);
    }
    out[(size_t)b*128 + f] = sigmoidf_((a0+a1)+(a2+a3));
}

// ---------------------------------------------------------------------------
extern "C" void kernel_launch(void* const* d_in, const int* in_sizes, int n_in,
                              void* d_out, int out_size, void* d_ws, size_t ws_size,
                              hipStream_t stream)
{
    const float* src   = (const float*)d_in[0];
    const float* w1w   = (const float*)d_in[1];
    const float* w1b   = (const float*)d_in[2];
    const float* w2w   = (const float*)d_in[3];
    const float* w2b   = (const float*)d_in[4];
    const float* meta  = (const float*)d_in[5];
    const float* pos   = (const float*)d_in[6];
    const float* Wq    = (const float*)d_in[7];
    const float* Wk    = (const float*)d_in[8];
    const float* Wv    = (const float*)d_in[9];
    const float* Wo    = (const float*)d_in[10];
    const float* bq    = (const float*)d_in[11];
    const float* bk    = (const float*)d_in[12];
    const float* bv    = (const float*)d_in[13];
    const float* bo    = (const float*)d_in[14];
    const float* l1s   = (const float*)d_in[15];
    const float* l1b   = (const float*)d_in[16];
    const float* W1    = (const float*)d_in[17];
    const float* b1    = (const float*)d_in[18];
    const float* W2    = (const float*)d_in[19];
    const float* b2    = (const float*)d_in[20];
    const float* l2s   = (const float*)d_in[21];
    const float* l2b   = (const float*)d_in[22];
    const float* Wih   = (const float*)d_in[23];
    const float* Whh   = (const float*)d_in[24];
    const float* bih   = (const float*)d_in[25];
    const float* bhh   = (const float*)d_in[26];
    const float* hini  = (const float*)d_in[27];
    const float* fW    = (const float*)d_in[28];
    const float* fb    = (const float*)d_in[29];

    float* ws = (float*)d_ws;
    float* x  = ws;                 // 110592
    float* q  = x  + 110592;
    float* k  = q  + 110592;
    float* v  = k  + 110592;
    float* o  = v  + 110592;
    float* GI = o  + 110592;        // 294912
    float* h0 = GI + 294912;        // 12288
    float* h1 = h0 + 12288;

    k_autodis_qkv<<<144, 128, 0, stream>>>(src, w1w, w1b, w2w, w2b, meta, pos,
                                           Wq, Wk, Wv, bq, bk, bv, x, q, k, v);

    for (int l = 0; l < NLn; ++l) {
        k_attn<<<Bn*NHn*72, 256, 0, stream>>>(q, k, v, o);
        bool nx = (l + 1 < NLn);
        k_post<<<144, 128, 0, stream>>>(x, o, Wo + l*36, bo + l*6,
                                        l1s + l*6, l1b + l*6,
                                        W1 + l*72, b1 + l*12,
                                        W2 + l*72, b2 + l*6,
                                        l2s + l*6, l2b + l*6, x,
                                        nx ? Wq + (l+1)*36 : nullptr,
                                        nx ? Wk + (l+1)*36 : nullptr,
                                        nx ? Wv + (l+1)*36 : nullptr,
                                        nx ? bq + (l+1)*6  : nullptr,
                                        nx ? bk + (l+1)*6  : nullptr,
                                        nx ? bv + (l+1)*6  : nullptr,
                                        q, k, v);
    }

    k_gi<<<8*144, 256, 0, stream>>>(x, Wih, bih, GI);

    const float* hcur = hini;
    float* hb[2] = {h0, h1};
    for (int w = 0; w < 8; ++w) {
        float* hn = hb[w & 1];
        k_gru<<<384, 192, 0, stream>>>(hcur, GI + (size_t)w*16*2304, Whh, bhh, hn);
        hcur = hn;
    }

    k_final<<<16, 128, 0, stream>>>(hcur, fW, fb, (float*)d_out);
}